// Round 2
// baseline (2734.694 us; speedup 1.0000x reference)
//
#include <hip/hip_runtime.h>
#include <hip/hip_bf16.h>

typedef __attribute__((ext_vector_type(8))) short short8;
typedef __attribute__((ext_vector_type(4))) float floatx4;

#define NEGF 1.0e12f

__device__ __forceinline__ float bf2f(unsigned short u){
  union { unsigned int i; float f; } x; x.i = ((unsigned int)u) << 16; return x.f;
}
__device__ __forceinline__ unsigned short f2bf(float f){
  union { float f; unsigned int i; } x; x.f = f;
  unsigned int i = x.i;
  i += 0x7fffu + ((i >> 16) & 1u);   // round-to-nearest-even
  return (unsigned short)(i >> 16);
}

#define GLD_LDS16(g, l) __builtin_amdgcn_global_load_lds( \
    (const __attribute__((address_space(1))) void*)(g),   \
    (__attribute__((address_space(3))) void*)(l), 16, 0, 0)

// ---------------- generic bf16 MFMA GEMM: C[M,N] = A[M,K] @ B[N,K]^T ----------------
// A: [M x K] bf16 row-major, M % 128 == 0, K % 64 == 0
// B: [Npad x K] bf16 row-major (Npad = ntn*128, rows >= N zero-padded)
// EPI 0: fp32 out + bias(nullable)    EPI 1: bf16 out + bias
// EPI 2: bf16 out + bias + tanh       EPI 3: logits row (ldc=45050): col<N -> v+bias, 0->-NEG; [N,ldc) -> -NEG
template<int EPI>
__global__ __launch_bounds__(256) void gemm_bf16(
    const unsigned short* __restrict__ A, const unsigned short* __restrict__ B,
    float* __restrict__ Cf, unsigned short* __restrict__ Cb,
    const float* __restrict__ bias, int N, int K, int ldc, int ntn)
{
  __shared__ unsigned short Al[128*64];
  __shared__ unsigned short Bl[128*64];
  int bid = blockIdx.x;
  int bm = bid / ntn, bn = bid % ntn;
  int t = threadIdx.x;
  int w = t >> 6, l = t & 63;

  floatx4 acc[4][4];
#pragma unroll
  for (int i = 0; i < 4; ++i)
#pragma unroll
    for (int j = 0; j < 4; ++j) acc[i][j] = (floatx4){0.f, 0.f, 0.f, 0.f};

  const char* Ab = (const char*)A + (size_t)bm * 128 * K * 2;
  const char* Bb = (const char*)B + (size_t)bn * 128 * K * 2;
  const int rowb = K * 2;
  const int r0 = t >> 3;            // 0..31
  const int cbyte = (t & 7) * 16;
  char* AlB = (char*)Al;
  char* BlB = (char*)Bl;
  const int wm = (w >> 1) * 64, wn = (w & 1) * 64;

  for (int kt = 0; kt < K; kt += 64) {
    __syncthreads();   // prior reads of LDS done
#pragma unroll
    for (int c = 0; c < 4; ++c) {
      int row = c * 32 + r0;
      GLD_LDS16(Ab + (size_t)row * rowb + kt * 2 + cbyte, AlB + c * 4096 + t * 16);
      GLD_LDS16(Bb + (size_t)row * rowb + kt * 2 + cbyte, BlB + c * 4096 + t * 16);
    }
    __syncthreads();   // waits vmcnt(0) before barrier -> staged data visible
#pragma unroll
    for (int kk = 0; kk < 64; kk += 32) {
      short8 af[4], bfv[4];
#pragma unroll
      for (int i = 0; i < 4; ++i)
        af[i] = *(const short8*)&Al[(wm + i * 16 + (l & 15)) * 64 + kk + ((l >> 4) << 3)];
#pragma unroll
      for (int j = 0; j < 4; ++j)
        bfv[j] = *(const short8*)&Bl[(wn + j * 16 + (l & 15)) * 64 + kk + ((l >> 4) << 3)];
#pragma unroll
      for (int i = 0; i < 4; ++i)
#pragma unroll
        for (int j = 0; j < 4; ++j)
          acc[i][j] = __builtin_amdgcn_mfma_f32_16x16x32_bf16(af[i], bfv[j], acc[i][j], 0, 0, 0);
    }
  }

  // epilogue: C/D layout col = lane&15, row = (lane>>4)*4 + r
  int mbase = bm * 128 + wm + ((l >> 4) << 2);
  int nbase = bn * 128 + wn + (l & 15);
#pragma unroll
  for (int j = 0; j < 4; ++j) {
    int col = nbase + j * 16;
#pragma unroll
    for (int i = 0; i < 4; ++i) {
#pragma unroll
      for (int r = 0; r < 4; ++r) {
        int row = mbase + i * 16 + r;
        float v = acc[i][j][r];
        if (EPI == 3) {
          size_t idx = (size_t)row * ldc + col;
          if (col < N) { float v2 = v + bias[col]; Cf[idx] = (v2 == 0.f) ? -NEGF : v2; }
          else if (col < ldc) Cf[idx] = -NEGF;
        } else if (col < N) {
          if (EPI == 0) {
            float bv = bias ? bias[col] : 0.f;
            Cf[(size_t)row * ldc + col] = v + bv;
          } else if (EPI == 1) {
            Cb[(size_t)row * ldc + col] = f2bf(v + bias[col]);
          } else {
            Cb[(size_t)row * ldc + col] = f2bf(tanhf(v + bias[col]));
          }
        }
      }
    }
  }
}

// ---------------- cast / pad kernels ----------------
__global__ void cast_pad_kernel(const float* __restrict__ src, unsigned short* __restrict__ dst,
                                int R, int C, int ld, int Cpad, long total){
  long i = (long)blockIdx.x * 256 + threadIdx.x;
  if (i >= total) return;
  int r = (int)(i / Cpad), c = (int)(i % Cpad);
  float v = (r < R && c < C) ? src[(size_t)r * ld + c] : 0.f;
  dst[i] = f2bf(v);
}

// emb: [B,T,E] -> time-major [T*B, 320] bf16 (zero pad cols 300..319)
__global__ void cast_emb_kernel(const float* __restrict__ trg, unsigned short* __restrict__ dst){
  int i = blockIdx.x * 256 + threadIdx.x;
  if (i >= 1024 * 320) return;
  int m = i / 320, e = i % 320;
  int tt = m >> 5, b = m & 31;
  float v = (e < 300) ? trg[((size_t)b * 32 + tt) * 300 + e] : 0.f;
  dst[i] = f2bf(v);
}

// Wr2^T: dst[h][e] = W_red[e][300+h], [512 x 320] bf16
__global__ void cast_wr2t_kernel(const float* __restrict__ wred, unsigned short* __restrict__ dst){
  int i = blockIdx.x * 256 + threadIdx.x;
  if (i >= 512 * 320) return;
  int h = i / 320, e = i % 320;
  float v = (e < 300) ? wred[(size_t)e * 812 + 300 + h] : 0.f;
  dst[i] = f2bf(v);
}

__global__ void init_kernel(const float* __restrict__ h0, const float* __restrict__ b_ih,
                            const float* __restrict__ b_hh,
                            float* __restrict__ h_buf0, float* __restrict__ ctx_buf0,
                            float* __restrict__ c_buf, float* __restrict__ bias_sum,
                            unsigned short* __restrict__ X1b){
  int i = blockIdx.x * 256 + threadIdx.x;
  if (i < 16384) { float v = h0[i]; h_buf0[i] = v; c_buf[i] = v; ctx_buf0[i] = 0.f; }
  if (i < 2048)  { bias_sum[i] = b_ih[i] + b_hh[i]; }
  if (i < 327680){ X1b[i] = 0; }  // bf16 zero
}

// ---------------- per-step: gates + LSTM pointwise ----------------
// gates[b][g*512+j] = P[t,b][g*512+j] + ctx @ M1^T + h @ Whh^T ; then LSTM cell.
__global__ __launch_bounds__(256) void step_gates(
    const float* __restrict__ P, const float* __restrict__ M1, const float* __restrict__ Whh,
    const float* __restrict__ ctx_in, const float* __restrict__ h_in,
    float* __restrict__ h_out, float* __restrict__ c_buf,
    unsigned short* __restrict__ HC, int t_step)
{
  int t = threadIdx.x;
  int kh = t & 1;
  int pair = t >> 1;       // 0..127
  int b = pair & 31;
  int j = blockIdx.x * 4 + (pair >> 5);
  const float4* x4 = (const float4*)((kh ? h_in : ctx_in) + b * 512);
  const float* W = kh ? Whh : M1;
  const float4* w0 = (const float4*)(W + (size_t)(j) * 512);
  const float4* w1 = (const float4*)(W + (size_t)(512 + j) * 512);
  const float4* w2 = (const float4*)(W + (size_t)(1024 + j) * 512);
  const float4* w3 = (const float4*)(W + (size_t)(1536 + j) * 512);
  float s0 = 0, s1 = 0, s2 = 0, s3 = 0;
#pragma unroll 4
  for (int k = 0; k < 128; ++k) {
    float4 xv = x4[k];
    float4 a0 = w0[k], a1 = w1[k], a2 = w2[k], a3 = w3[k];
    s0 += xv.x * a0.x + xv.y * a0.y + xv.z * a0.z + xv.w * a0.w;
    s1 += xv.x * a1.x + xv.y * a1.y + xv.z * a1.z + xv.w * a1.w;
    s2 += xv.x * a2.x + xv.y * a2.y + xv.z * a2.z + xv.w * a2.w;
    s3 += xv.x * a3.x + xv.y * a3.y + xv.z * a3.z + xv.w * a3.w;
  }
  s0 += __shfl_xor(s0, 1); s1 += __shfl_xor(s1, 1);
  s2 += __shfl_xor(s2, 1); s3 += __shfl_xor(s3, 1);
  if (kh == 0) {
    const float* Pr = P + ((size_t)t_step * 32 + b) * 2048;
    float gi = s0 + Pr[j];
    float gf = s1 + Pr[512 + j];
    float gg = s2 + Pr[1024 + j];
    float go = s3 + Pr[1536 + j];
    float c = c_buf[b * 512 + j];
    float ig = 1.f / (1.f + expf(-gi));
    float fg = 1.f / (1.f + expf(-gf));
    float og = 1.f / (1.f + expf(-go));
    float cn = fg * c + ig * tanhf(gg);
    float hn = og * tanhf(cn);
    c_buf[b * 512 + j] = cn;
    h_out[b * 512 + j] = hn;
    HC[((size_t)t_step * 32 + b) * 1024 + j] = f2bf(hn);
  }
}

// ---------------- per-step: energy -> softmax -> context ----------------
__global__ __launch_bounds__(256) void step_attn(
    const unsigned short* __restrict__ memb, const float* __restrict__ h,
    const int* __restrict__ mask,
    float* __restrict__ ctx_out, unsigned short* __restrict__ HC,
    float* __restrict__ e_out, float* __restrict__ a_out, int t_step)
{
  __shared__ float hs[512];
  __shared__ float es[400];
  __shared__ float red[8];
  int b = blockIdx.x;
  int t = threadIdx.x;
  hs[t] = h[b * 512 + t];
  hs[t + 256] = h[b * 512 + 256 + t];
  __syncthreads();
  size_t obase = (size_t)t_step * 12800 + b * 400;
  for (int s = t; s < 400; s += 256) {
    const unsigned short* mrow = memb + ((size_t)b * 400 + s) * 512;
    float acc = 0.f;
    for (int k = 0; k < 512; k += 8) {
      short8 v = *(const short8*)(mrow + k);
      acc += bf2f((unsigned short)v[0]) * hs[k + 0];
      acc += bf2f((unsigned short)v[1]) * hs[k + 1];
      acc += bf2f((unsigned short)v[2]) * hs[k + 2];
      acc += bf2f((unsigned short)v[3]) * hs[k + 3];
      acc += bf2f((unsigned short)v[4]) * hs[k + 4];
      acc += bf2f((unsigned short)v[5]) * hs[k + 5];
      acc += bf2f((unsigned short)v[6]) * hs[k + 6];
      acc += bf2f((unsigned short)v[7]) * hs[k + 7];
    }
    if (mask[b * 400 + s] == 0) acc = -NEGF;
    es[s] = acc;
    e_out[obase + s] = acc;
  }
  __syncthreads();
  float lm = -3.4e38f;
  for (int s = t; s < 400; s += 256) lm = fmaxf(lm, es[s]);
#pragma unroll
  for (int o = 32; o; o >>= 1) lm = fmaxf(lm, __shfl_xor(lm, o));
  if ((t & 63) == 0) red[t >> 6] = lm;
  __syncthreads();
  float m = fmaxf(fmaxf(red[0], red[1]), fmaxf(red[2], red[3]));
  float ls = 0.f;
  for (int s = t; s < 400; s += 256) { float e = expf(es[s] - m); es[s] = e; ls += e; }
#pragma unroll
  for (int o = 32; o; o >>= 1) ls += __shfl_xor(ls, o);
  if ((t & 63) == 0) red[4 + (t >> 6)] = ls;
  __syncthreads();
  float inv = 1.f / (red[4] + red[5] + red[6] + red[7]);
  for (int s = t; s < 400; s += 256) { float a = es[s] * inv; es[s] = a; a_out[obase + s] = a; }
  __syncthreads();
  float c0 = 0.f, c1 = 0.f;
  const unsigned short* mb = memb + (size_t)b * 400 * 512;
  for (int s = 0; s < 400; ++s) {
    float a = es[s];
    c0 += a * bf2f(mb[s * 512 + t]);
    c1 += a * bf2f(mb[s * 512 + 256 + t]);
  }
  ctx_out[b * 512 + t] = c0;
  ctx_out[b * 512 + 256 + t] = c1;
  size_t hrow = ((size_t)t_step * 32 + b) * 1024;
  HC[hrow + 512 + t] = f2bf(c0);
  HC[hrow + 512 + 256 + t] = f2bf(c1);
}

// ---------------- coverage: cov[t] = sum_{t'<t} attn[t'] ----------------
__global__ void cov_kernel(const float* __restrict__ attn, float* __restrict__ cov){
  int idx = blockIdx.x * 256 + threadIdx.x;   // b*400+s
  if (idx >= 12800) return;
  float acc = 0.f;
  for (int t = 0; t < 32; ++t) {
    cov[(size_t)t * 12800 + idx] = acc;
    acc += attn[(size_t)t * 12800 + idx];
  }
}

// ---------------- pointer scatter-max patch ----------------
__global__ __launch_bounds__(512) void pointer_kernel(
    const int* __restrict__ ext, const float* __restrict__ energ, float* __restrict__ logits)
{
  __shared__ int ids[400];
  __shared__ float es[400];
  int tb = blockIdx.x;          // row m = t*32+b
  int b = tb & 31;
  int tt = tb >> 5;
  int t = threadIdx.x;
  if (t < 400) {
    ids[t] = ext[b * 400 + t];
    es[t] = energ[(size_t)tt * 12800 + b * 400 + t];
  }
  __syncthreads();
  if (t < 400) {
    int id = ids[t];
    bool first = true;
    for (int s = 0; s < t; ++s) if (ids[s] == id) { first = false; break; }
    if (first) {
      float mx = es[t];
      for (int s = t + 1; s < 400; ++s) if (ids[s] == id) mx = fmaxf(mx, es[s]);
      if (mx != -NEGF) {   // all-masked id behaves as absent
        float* p = &logits[(size_t)tb * 45050 + id];
        float base = 0.f;
        if (id < 45000) { float cur = *p; base = (cur == -NEGF) ? 0.f : cur; }
        float nv = base + mx;
        *p = (nv == 0.f) ? -NEGF : nv;
      }
    }
  }
}

// ---------------- host launcher ----------------
extern "C" void kernel_launch(void* const* d_in, const int* in_sizes, int n_in,
                              void* d_out, int out_size, void* d_ws, size_t ws_size,
                              hipStream_t stream) {
  const float* trg   = (const float*)d_in[0];
  const int*   ext   = (const int*)d_in[1];
  const float* inits = (const float*)d_in[2];
  const float* enc   = (const float*)d_in[3];
  const int*   mask  = (const int*)d_in[4];
  const float* W_enc = (const float*)d_in[5];
  const float* b_enc = (const float*)d_in[6];
  const float* W_red = (const float*)d_in[7];
  const float* b_red = (const float*)d_in[8];
  const float* W_ih  = (const float*)d_in[9];
  const float* W_hh  = (const float*)d_in[10];
  const float* b_ih  = (const float*)d_in[11];
  const float* b_hh  = (const float*)d_in[12];
  const float* W_cat = (const float*)d_in[13];
  const float* b_cat = (const float*)d_in[14];
  const float* W_log = (const float*)d_in[15];
  const float* b_log = (const float*)d_in[16];

  float* out = (float*)d_out;
  float* out_logits = out;                       // [1024 x 45050]
  float* out_attn   = out + 46131200;            // [32 x 32 x 400]
  float* out_cov    = out_attn + 409600;
  float* out_energy = out_cov + 409600;

  char* ws = (char*)d_ws;
  size_t o = 0;
  auto alloc = [&](size_t bytes) { void* p = ws + o; o += (bytes + 255) & ~(size_t)255; return p; };
  unsigned short* mem_b   = (unsigned short*)alloc(12800ULL * 512 * 2);
  unsigned short* enc_b   = (unsigned short*)alloc(12800ULL * 512 * 2);
  unsigned short* W_enc_b = (unsigned short*)alloc(512ULL * 512 * 2);
  unsigned short* emb_b   = (unsigned short*)alloc(1024ULL * 320 * 2);
  unsigned short* Wr1_b   = (unsigned short*)alloc(384ULL * 320 * 2);
  unsigned short* X1_b    = (unsigned short*)alloc(1024ULL * 320 * 2);
  unsigned short* W_ih_b  = (unsigned short*)alloc(2048ULL * 320 * 2);
  unsigned short* Wr2T_b  = (unsigned short*)alloc(512ULL * 320 * 2);
  unsigned short* W_cat_b = (unsigned short*)alloc(512ULL * 1024 * 2);
  unsigned short* W_log_b = (unsigned short*)alloc(45056ULL * 512 * 2);
  unsigned short* A_log   = (unsigned short*)alloc(1024ULL * 512 * 2);
  unsigned short* HC_b    = (unsigned short*)alloc(1024ULL * 1024 * 2);
  float* P        = (float*)alloc(1024ULL * 2048 * 4);
  float* M1       = (float*)alloc(2048ULL * 512 * 4);
  float* h_buf0   = (float*)alloc(32ULL * 512 * 4);
  float* h_buf1   = (float*)alloc(32ULL * 512 * 4);
  float* ctx_buf0 = (float*)alloc(32ULL * 512 * 4);
  float* ctx_buf1 = (float*)alloc(32ULL * 512 * 4);
  float* c_buf    = (float*)alloc(32ULL * 512 * 4);
  float* bias_sum = (float*)alloc(2048ULL * 4);
  float* h_bufs[2]   = { h_buf0, h_buf1 };
  float* ctx_bufs[2] = { ctx_buf0, ctx_buf1 };

  auto blocks = [](long total) { return (int)((total + 255) / 256); };

  // init + casts
  init_kernel<<<blocks(327680), 256, 0, stream>>>(inits, b_ih, b_hh, h_buf0, ctx_buf0, c_buf, bias_sum, X1_b);
  cast_pad_kernel<<<blocks(12800L*512), 256, 0, stream>>>(enc,   enc_b,   12800, 512, 512, 512, 12800L*512);
  cast_pad_kernel<<<blocks(512L*512),   256, 0, stream>>>(W_enc, W_enc_b, 512,   512, 512, 512, 512L*512);
  cast_pad_kernel<<<blocks(384L*320),   256, 0, stream>>>(W_red, Wr1_b,   300,   300, 812, 320, 384L*320);
  cast_pad_kernel<<<blocks(2048L*320),  256, 0, stream>>>(W_ih,  W_ih_b,  2048,  300, 300, 320, 2048L*320);
  cast_pad_kernel<<<blocks(512L*1024),  256, 0, stream>>>(W_cat, W_cat_b, 512,  1024, 1024, 1024, 512L*1024);
  cast_pad_kernel<<<blocks(45056L*512), 256, 0, stream>>>(W_log, W_log_b, 45000, 512, 512, 512, 45056L*512);
  cast_emb_kernel<<<blocks(1024L*320), 256, 0, stream>>>(trg, emb_b);
  cast_wr2t_kernel<<<blocks(512L*320), 256, 0, stream>>>(W_red, Wr2T_b);

  // batched pre-GEMMs
  gemm_bf16<1><<<100 * 4, 256, 0, stream>>>(enc_b, W_enc_b, nullptr, mem_b, b_enc, 512, 512, 512, 4);
  gemm_bf16<1><<<8 * 3,   256, 0, stream>>>(emb_b, Wr1_b, nullptr, X1_b, b_red, 300, 320, 320, 3);
  gemm_bf16<0><<<8 * 16,  256, 0, stream>>>(X1_b, W_ih_b, P, nullptr, bias_sum, 2048, 320, 2048, 16);
  gemm_bf16<0><<<16 * 4,  256, 0, stream>>>(W_ih_b, Wr2T_b, M1, nullptr, nullptr, 512, 320, 512, 4);

  // sequential recurrence
  int p = 0;
  for (int t = 0; t < 32; ++t) {
    step_gates<<<128, 256, 0, stream>>>(P, M1, W_hh, ctx_bufs[p], h_bufs[p],
                                        h_bufs[1 - p], c_buf, HC_b, t);
    step_attn<<<32, 256, 0, stream>>>(mem_b, h_bufs[1 - p], mask, ctx_bufs[1 - p],
                                      HC_b, out_energy, out_attn, t);
    p ^= 1;
  }

  // epilogue
  cov_kernel<<<50, 256, 0, stream>>>(out_attn, out_cov);
  gemm_bf16<2><<<8 * 4,   256, 0, stream>>>(HC_b, W_cat_b, nullptr, A_log, b_cat, 512, 1024, 512, 4);
  gemm_bf16<3><<<8 * 352, 256, 0, stream>>>(A_log, W_log_b, out_logits, nullptr, b_log, 45000, 512, 45050, 352);
  pointer_kernel<<<1024, 512, 0, stream>>>(ext, out_energy, out_logits);
}

// Round 3
// 1886.720 us; speedup vs baseline: 1.4494x; 1.4494x over previous
//
#include <hip/hip_runtime.h>
#include <hip/hip_bf16.h>

typedef _Float16 h2 __attribute__((ext_vector_type(2)));
typedef _Float16 h8 __attribute__((ext_vector_type(8)));
typedef __attribute__((ext_vector_type(4))) float floatx4;

#define NEGF 1.0e12f

#if __has_builtin(__builtin_amdgcn_fdot2)
#define DOT2(a,b,c) __builtin_amdgcn_fdot2((a),(b),(c),false)
#else
static __device__ __forceinline__ float DOT2(h2 a, h2 b, float c){
  return c + (float)a[0]*(float)b[0] + (float)a[1]*(float)b[1];
}
#endif

__device__ __forceinline__ float dot8(h8 a, h8 b, float c){
  h2 a0 = {a[0],a[1]}, a1 = {a[2],a[3]}, a2 = {a[4],a[5]}, a3 = {a[6],a[7]};
  h2 b0 = {b[0],b[1]}, b1 = {b[2],b[3]}, b2 = {b[4],b[5]}, b3 = {b[6],b[7]};
  c = DOT2(a0,b0,c); c = DOT2(a1,b1,c); c = DOT2(a2,b2,c); c = DOT2(a3,b3,c);
  return c;
}

#define GLD_LDS16(g, l) __builtin_amdgcn_global_load_lds( \
    (const __attribute__((address_space(1))) void*)(g),   \
    (__attribute__((address_space(3))) void*)(l), 16, 0, 0)

// ---------------- generic f16 MFMA GEMM: C[M,N] = A[M,K] @ B[N,K]^T ----------------
// A: [M x K] f16 row-major, M % 128 == 0, K % 64 == 0
// B: [Npad x K] f16 row-major (Npad = ntn*128, rows >= N zero-padded)
// block order: bm = bid % ntm (B-tile shared by consecutive blocks)
// LDS tiles XOR-swizzled: LDS(row, cb) holds G(row, cb ^ ((row&7)<<4))
// EPI 0: fp32 out + bias(nullable)    EPI 1: f16 out + bias(nullable)
// EPI 2: f16 out + bias + tanh       EPI 3: logits row: col<N -> v+bias (0 -> -NEG); [N,ldc) -> -NEG
template<int EPI>
__global__ __launch_bounds__(256) void gemm_f16(
    const _Float16* __restrict__ A, const _Float16* __restrict__ B,
    float* __restrict__ Cf, _Float16* __restrict__ Ch,
    const float* __restrict__ bias, int N, int K, int ldc, int ntm)
{
  __shared__ _Float16 Al[128*64];
  __shared__ _Float16 Bl[128*64];
  int bid = blockIdx.x;
  int bm = bid % ntm, bn = bid / ntm;
  int t = threadIdx.x;
  int w = t >> 6, l = t & 63;

  floatx4 acc[4][4];
#pragma unroll
  for (int i = 0; i < 4; ++i)
#pragma unroll
    for (int j = 0; j < 4; ++j) acc[i][j] = (floatx4){0.f, 0.f, 0.f, 0.f};

  const char* Ab = (const char*)A + (size_t)bm * 128 * K * 2;
  const char* Bb = (const char*)B + (size_t)bn * 128 * K * 2;
  const int rowb = K * 2;
  const int r0 = t >> 3;            // 0..31 (row within 32-row chunk)
  // pre-swizzled global column byte (inverse of read-side swizzle)
  const int cbyte = ((t & 7) * 16) ^ (((t >> 3) & 7) << 4);
  char* AlB = (char*)Al;
  char* BlB = (char*)Bl;
  const int wm = (w >> 1) * 64, wn = (w & 1) * 64;

  for (int kt = 0; kt < K; kt += 64) {
    __syncthreads();
#pragma unroll
    for (int c = 0; c < 4; ++c) {
      int row = c * 32 + r0;
      GLD_LDS16(Ab + (size_t)row * rowb + kt * 2 + cbyte, AlB + c * 4096 + t * 16);
      GLD_LDS16(Bb + (size_t)row * rowb + kt * 2 + cbyte, BlB + c * 4096 + t * 16);
    }
    __syncthreads();
#pragma unroll
    for (int kk = 0; kk < 64; kk += 32) {
      h8 af[4], bfv[4];
#pragma unroll
      for (int i = 0; i < 4; ++i) {
        int ra = wm + i * 16 + (l & 15);
        int cb = ((kk << 1) + ((l >> 4) << 4)) ^ ((ra & 7) << 4);
        af[i] = *(const h8*)(AlB + ra * 128 + cb);
      }
#pragma unroll
      for (int j = 0; j < 4; ++j) {
        int ra = wn + j * 16 + (l & 15);
        int cb = ((kk << 1) + ((l >> 4) << 4)) ^ ((ra & 7) << 4);
        bfv[j] = *(const h8*)(BlB + ra * 128 + cb);
      }
#pragma unroll
      for (int i = 0; i < 4; ++i)
#pragma unroll
        for (int j = 0; j < 4; ++j)
          acc[i][j] = __builtin_amdgcn_mfma_f32_16x16x32_f16(af[i], bfv[j], acc[i][j], 0, 0, 0);
    }
  }

  // epilogue: C/D layout col = lane&15, row = (lane>>4)*4 + r
  int mbase = bm * 128 + wm + ((l >> 4) << 2);
  int nbase = bn * 128 + wn + (l & 15);
#pragma unroll
  for (int j = 0; j < 4; ++j) {
    int col = nbase + j * 16;
#pragma unroll
    for (int i = 0; i < 4; ++i) {
#pragma unroll
      for (int r = 0; r < 4; ++r) {
        int row = mbase + i * 16 + r;
        float v = acc[i][j][r];
        if (EPI == 3) {
          size_t idx = (size_t)row * ldc + col;
          if (col < N) { float v2 = v + bias[col]; Cf[idx] = (v2 == 0.f) ? -NEGF : v2; }
          else if (col < ldc) Cf[idx] = -NEGF;
        } else if (col < N) {
          float bv = bias ? bias[col] : 0.f;
          if (EPI == 0)      Cf[(size_t)row * ldc + col] = v + bv;
          else if (EPI == 1) Ch[(size_t)row * ldc + col] = (_Float16)(v + bv);
          else               Ch[(size_t)row * ldc + col] = (_Float16)tanhf(v + bv);
        }
      }
    }
  }
}

// ---------------- cast / pad kernels ----------------
__global__ void cast_pad_kernel(const float* __restrict__ src, _Float16* __restrict__ dst,
                                int R, int C, int ld_src, int Cpad, int ld_dst, long total){
  long i = (long)blockIdx.x * 256 + threadIdx.x;
  if (i >= total) return;
  int r = (int)(i / Cpad), c = (int)(i % Cpad);
  float v = (r < R && c < C) ? src[(size_t)r * ld_src + c] : 0.f;
  dst[(size_t)r * ld_dst + c] = (_Float16)v;
}

// emb: [B,T,E] -> time-major [T*B, 320] f16 (zero pad cols 300..319)
__global__ void cast_emb_kernel(const float* __restrict__ trg, _Float16* __restrict__ dst){
  int i = blockIdx.x * 256 + threadIdx.x;
  if (i >= 1024 * 320) return;
  int m = i / 320, e = i % 320;
  int tt = m >> 5, b = m & 31;
  float v = (e < 300) ? trg[((size_t)b * 32 + tt) * 300 + e] : 0.f;
  dst[i] = (_Float16)v;
}

// Wr2^T: dst[h][e] = W_red[e][300+h], [512 x 320] f16
__global__ void cast_wr2t_kernel(const float* __restrict__ wred, _Float16* __restrict__ dst){
  int i = blockIdx.x * 256 + threadIdx.x;
  if (i >= 512 * 320) return;
  int h = i / 320, e = i % 320;
  float v = (e < 300) ? wred[(size_t)e * 812 + 300 + h] : 0.f;
  dst[i] = (_Float16)v;
}

__global__ void init_kernel(const float* __restrict__ h0, const float* __restrict__ b_ih,
                            const float* __restrict__ b_hh,
                            _Float16* __restrict__ HCz, float* __restrict__ c_buf,
                            float* __restrict__ bias_sum, _Float16* __restrict__ X1h){
  int i = blockIdx.x * 256 + threadIdx.x;
  if (i < 32768) {  // HCz row 0 = [h0 | 0]
    int b = i >> 10, k = i & 1023;
    HCz[i] = (k < 512) ? (_Float16)h0[b * 512 + k] : (_Float16)0.f;
  }
  if (i < 16384) c_buf[i] = h0[i];
  if (i < 2048)  bias_sum[i] = b_ih[i] + b_hh[i];
  if (i < 327680) X1h[i] = (_Float16)0.f;
}

// ---------------- per-step: gates + LSTM pointwise ----------------
// z = HCz[ts] (=[h|ctx] f16, [32][1024]); gates = P[ts] + z @ Wz^T; Wz=[Whh|M1]
// grid 512 (block = j in [0,512)), 256 threads: b=t&31, rs=(t>>5)&3 (gate), kh=t>>7 (k half)
__global__ __launch_bounds__(256) void step_gates(
    _Float16* __restrict__ HCz, const float* __restrict__ P,
    const _Float16* __restrict__ Wz, float* __restrict__ c_buf, int ts)
{
  __shared__ _Float16 zi[128*32*8];   // zi[kb][b][8] = z[b][kb*8..+8]
  __shared__ float part1[4][32];
  __shared__ float tot[4][32];
  int t = threadIdx.x;
  int j = blockIdx.x;
  const _Float16* zsrc = HCz + (size_t)ts * 32768;
  // stage z interleaved: lane idx = v*256+t -> (b = idx&31, kb = idx>>5); dest linear = idx*16B
#pragma unroll
  for (int v = 0; v < 16; ++v) {
    int idx = v * 256 + t;
    int bs = idx & 31, kb = idx >> 5;
    GLD_LDS16(zsrc + (size_t)bs * 1024 + kb * 8, (char*)zi + (size_t)idx * 16);
  }
  __syncthreads();
  int b = t & 31, rs = (t >> 5) & 3, kh = t >> 7;
  const _Float16* wr = Wz + (size_t)(rs * 512 + j) * 1024;
  float s = 0.f;
#pragma unroll 4
  for (int kb = kh * 64; kb < kh * 64 + 64; ++kb) {
    h8 zv = *(const h8*)&zi[(kb * 32 + b) * 8];
    h8 wv = *(const h8*)&wr[kb * 8];
    s = dot8(zv, wv, s);
  }
  if (kh) part1[rs][b] = s;
  __syncthreads();
  if (!kh) tot[rs][b] = s + part1[rs][b];
  __syncthreads();
  if (t < 32) {
    const float* Pr = P + ((size_t)ts * 32 + t) * 2048;
    float gi = tot[0][t] + Pr[j];
    float gf = tot[1][t] + Pr[512 + j];
    float gg = tot[2][t] + Pr[1024 + j];
    float go = tot[3][t] + Pr[1536 + j];
    float c = c_buf[t * 512 + j];
    float ig = 1.f / (1.f + expf(-gi));
    float fg = 1.f / (1.f + expf(-gf));
    float og = 1.f / (1.f + expf(-go));
    float cn = fg * c + ig * tanhf(gg);
    float hn = og * tanhf(cn);
    c_buf[t * 512 + j] = cn;
    HCz[(size_t)(ts + 1) * 32768 + t * 1024 + j] = (_Float16)hn;
  }
}

// ---------------- per-step: energy -> softmax -> context ----------------
// 32 blocks (b) x 512 threads
__global__ __launch_bounds__(512) void step_attn(
    const _Float16* __restrict__ memh, _Float16* __restrict__ HCz,
    const int* __restrict__ mask, float* __restrict__ e_out,
    float* __restrict__ a_out, int ts)
{
  __shared__ _Float16 hh[512];
  __shared__ float es[400];
  __shared__ float red[16];
  int b = blockIdx.x, t = threadIdx.x;
  const _Float16* hrow = HCz + (size_t)(ts + 1) * 32768 + b * 1024;
  hh[t] = hrow[t];
  __syncthreads();
  int w = t >> 6, l = t & 63;
  const _Float16* mb = memh + (size_t)b * 400 * 512;
  size_t obase = (size_t)ts * 12800 + b * 400;
  h8 hv = *(const h8*)&hh[l * 8];
  for (int r = 0; r < 50; ++r) {
    int s = w * 50 + r;
    h8 mv = *(const h8*)&mb[(size_t)s * 512 + l * 8];
    float e = dot8(mv, hv, 0.f);
#pragma unroll
    for (int o = 32; o; o >>= 1) e += __shfl_xor(e, o);
    if (l == 0) {
      if (mask[b * 400 + s] == 0) e = -NEGF;
      es[s] = e;
      e_out[obase + s] = e;
    }
  }
  __syncthreads();
  float v = (t < 400) ? es[t] : -3.4e38f;
  float m = v;
#pragma unroll
  for (int o = 32; o; o >>= 1) m = fmaxf(m, __shfl_xor(m, o));
  if (l == 0) red[w] = m;
  __syncthreads();
  m = red[0];
#pragma unroll
  for (int q = 1; q < 8; ++q) m = fmaxf(m, red[q]);
  float p = (t < 400) ? expf(v - m) : 0.f;
  if (t < 400) es[t] = p;
  float sum = p;
#pragma unroll
  for (int o = 32; o; o >>= 1) sum += __shfl_xor(sum, o);
  if (l == 0) red[8 + w] = sum;
  __syncthreads();
  float tot = red[8];
#pragma unroll
  for (int q = 9; q < 16; ++q) tot += red[q];
  float inv = 1.f / tot;
  if (t < 400) a_out[obase + t] = p * inv;
  __syncthreads();
  // context: d = t (0..511)
  float acc = 0.f;
#pragma unroll 4
  for (int s = 0; s < 400; ++s)
    acc += es[s] * (float)mb[(size_t)s * 512 + t];
  HCz[(size_t)(ts + 1) * 32768 + b * 1024 + 512 + t] = (_Float16)(acc * inv);
}

// ---------------- coverage ----------------
__global__ void cov_kernel(const float* __restrict__ attn, float* __restrict__ cov){
  int idx = blockIdx.x * 256 + threadIdx.x;   // b*400+s
  if (idx >= 12800) return;
  float acc = 0.f;
  for (int t = 0; t < 32; ++t) {
    cov[(size_t)t * 12800 + idx] = acc;
    acc += attn[(size_t)t * 12800 + idx];
  }
}

// ---------------- pointer scatter-max patch ----------------
__global__ __launch_bounds__(512) void pointer_kernel(
    const int* __restrict__ ext, const float* __restrict__ energ, float* __restrict__ logits)
{
  __shared__ int ids[400];
  __shared__ float es[400];
  int tb = blockIdx.x;          // row m = t*32+b
  int b = tb & 31;
  int tt = tb >> 5;
  int t = threadIdx.x;
  if (t < 400) {
    ids[t] = ext[b * 400 + t];
    es[t] = energ[(size_t)tt * 12800 + b * 400 + t];
  }
  __syncthreads();
  if (t < 400) {
    int id = ids[t];
    bool first = true;
    for (int s = 0; s < t; ++s) if (ids[s] == id) { first = false; break; }
    if (first) {
      float mx = es[t];
      for (int s = t + 1; s < 400; ++s) if (ids[s] == id) mx = fmaxf(mx, es[s]);
      if (mx != -NEGF) {
        float* p = &logits[(size_t)tb * 45050 + id];
        float base = 0.f;
        if (id < 45000) { float cur = *p; base = (cur == -NEGF) ? 0.f : cur; }
        float nv = base + mx;
        *p = (nv == 0.f) ? -NEGF : nv;
      }
    }
  }
}

// ---------------- host launcher ----------------
extern "C" void kernel_launch(void* const* d_in, const int* in_sizes, int n_in,
                              void* d_out, int out_size, void* d_ws, size_t ws_size,
                              hipStream_t stream) {
  const float* trg   = (const float*)d_in[0];
  const int*   ext   = (const int*)d_in[1];
  const float* inits = (const float*)d_in[2];
  const float* enc   = (const float*)d_in[3];
  const int*   mask  = (const int*)d_in[4];
  const float* W_enc = (const float*)d_in[5];
  const float* b_enc = (const float*)d_in[6];
  const float* W_red = (const float*)d_in[7];
  const float* b_red = (const float*)d_in[8];
  const float* W_ih  = (const float*)d_in[9];
  const float* W_hh  = (const float*)d_in[10];
  const float* b_ih  = (const float*)d_in[11];
  const float* b_hh  = (const float*)d_in[12];
  const float* W_cat = (const float*)d_in[13];
  const float* b_cat = (const float*)d_in[14];
  const float* W_log = (const float*)d_in[15];
  const float* b_log = (const float*)d_in[16];

  float* out = (float*)d_out;
  float* out_logits = out;                       // [1024 x 45050]
  float* out_attn   = out + 46131200;            // [32 x 32 x 400]
  float* out_cov    = out_attn + 409600;
  float* out_energy = out_cov + 409600;

  char* ws = (char*)d_ws;
  size_t o = 0;
  auto alloc = [&](size_t bytes) { void* p = ws + o; o += (bytes + 255) & ~(size_t)255; return p; };
  _Float16* mem_h   = (_Float16*)alloc(12800ULL * 512 * 2);
  _Float16* enc_h   = (_Float16*)alloc(12800ULL * 512 * 2);
  _Float16* W_enc_h = (_Float16*)alloc(512ULL * 512 * 2);
  _Float16* emb_h   = (_Float16*)alloc(1024ULL * 320 * 2);
  _Float16* Wr1_h   = (_Float16*)alloc(384ULL * 320 * 2);
  _Float16* X1_h    = (_Float16*)alloc(1024ULL * 320 * 2);
  _Float16* W_ih_h  = (_Float16*)alloc(2048ULL * 320 * 2);
  _Float16* Wr2T_h  = (_Float16*)alloc(512ULL * 320 * 2);
  _Float16* W_cat_h = (_Float16*)alloc(512ULL * 1024 * 2);
  _Float16* W_log_h = (_Float16*)alloc(45056ULL * 512 * 2);
  _Float16* A_log_h = (_Float16*)alloc(1024ULL * 512 * 2);
  _Float16* HCz     = (_Float16*)alloc(33ULL * 32768 * 2);  // row0 init, rows 1..32 = steps
  _Float16* Wz      = (_Float16*)alloc(2048ULL * 1024 * 2); // [Whh | M1]
  float* P        = (float*)alloc(1024ULL * 2048 * 4);
  float* c_buf    = (float*)alloc(32ULL * 512 * 4);
  float* bias_sum = (float*)alloc(2048ULL * 4);

  auto blocks = [](long total) { return (int)((total + 255) / 256); };

  // init + casts
  init_kernel<<<blocks(327680), 256, 0, stream>>>(inits, b_ih, b_hh, HCz, c_buf, bias_sum, X1_h);
  cast_pad_kernel<<<blocks(12800L*512), 256, 0, stream>>>(enc,   enc_h,   12800, 512, 512, 512, 512, 12800L*512);
  cast_pad_kernel<<<blocks(512L*512),   256, 0, stream>>>(W_enc, W_enc_h, 512,   512, 512, 512, 512, 512L*512);
  cast_pad_kernel<<<blocks(384L*320),   256, 0, stream>>>(W_red, Wr1_h,   300,   300, 812, 320, 320, 384L*320);
  cast_pad_kernel<<<blocks(2048L*320),  256, 0, stream>>>(W_ih,  W_ih_h,  2048,  300, 300, 320, 320, 2048L*320);
  cast_pad_kernel<<<blocks(512L*1024),  256, 0, stream>>>(W_cat, W_cat_h, 512,  1024, 1024, 1024, 1024, 512L*1024);
  cast_pad_kernel<<<blocks(45056L*512), 256, 0, stream>>>(W_log, W_log_h, 45000, 512, 512, 512, 512, 45056L*512);
  cast_pad_kernel<<<blocks(2048L*512),  256, 0, stream>>>(W_hh,  Wz,      2048,  512, 512, 512, 1024, 2048L*512);
  cast_emb_kernel<<<blocks(1024L*320), 256, 0, stream>>>(trg, emb_h);
  cast_wr2t_kernel<<<blocks(512L*320), 256, 0, stream>>>(W_red, Wr2T_h);

  // batched pre-GEMMs
  gemm_f16<1><<<400, 256, 0, stream>>>(enc_h, W_enc_h, nullptr, mem_h, b_enc, 512, 512, 512, 100);
  gemm_f16<1><<<24,  256, 0, stream>>>(emb_h, Wr1_h, nullptr, X1_h, b_red, 300, 320, 320, 8);
  gemm_f16<0><<<128, 256, 0, stream>>>(X1_h, W_ih_h, P, nullptr, bias_sum, 2048, 320, 2048, 8);
  gemm_f16<1><<<64,  256, 0, stream>>>(W_ih_h, Wr2T_h, nullptr, Wz + 512, nullptr, 512, 320, 1024, 16); // M1 into Wz cols 512..1023

  // sequential recurrence
  for (int t = 0; t < 32; ++t) {
    step_gates<<<512, 256, 0, stream>>>(HCz, P, Wz, c_buf, t);
    step_attn<<<32, 512, 0, stream>>>(mem_h, HCz, mask, out_energy, out_attn, t);
  }

  // epilogue
  cov_kernel<<<50, 256, 0, stream>>>(out_attn, out_cov);
  gemm_f16<2><<<32, 256, 0, stream>>>(HCz + 32768, W_cat_h, nullptr, A_log_h, b_cat, 512, 1024, 512, 8);
  gemm_f16<3><<<2816, 256, 0, stream>>>(A_log_h, W_log_h, out_logits, nullptr, b_log, 45000, 512, 45050, 8);
  pointer_kernel<<<1024, 512, 0, stream>>>(ext, out_energy, out_logits);
}

// Round 4
// 1852.008 us; speedup vs baseline: 1.4766x; 1.0187x over previous
//
#include <hip/hip_runtime.h>
#include <hip/hip_bf16.h>

typedef _Float16 h2 __attribute__((ext_vector_type(2)));
typedef _Float16 h8 __attribute__((ext_vector_type(8)));
typedef __attribute__((ext_vector_type(4))) float floatx4;

#define NEGF 1.0e12f

#if __has_builtin(__builtin_amdgcn_fdot2)
#define DOT2(a,b,c) __builtin_amdgcn_fdot2((a),(b),(c),false)
#else
static __device__ __forceinline__ float DOT2(h2 a, h2 b, float c){
  return c + (float)a[0]*(float)b[0] + (float)a[1]*(float)b[1];
}
#endif

__device__ __forceinline__ float dot8(h8 a, h8 b, float c){
  h2 a0 = {a[0],a[1]}, a1 = {a[2],a[3]}, a2 = {a[4],a[5]}, a3 = {a[6],a[7]};
  h2 b0 = {b[0],b[1]}, b1 = {b[2],b[3]}, b2 = {b[4],b[5]}, b3 = {b[6],b[7]};
  c = DOT2(a0,b0,c); c = DOT2(a1,b1,c); c = DOT2(a2,b2,c); c = DOT2(a3,b3,c);
  return c;
}

__device__ __forceinline__ unsigned short f16bits(float x){
  union { _Float16 h; unsigned short u; } cv; cv.h = (_Float16)x; return cv.u;
}

#define GLD_LDS16(g, l) __builtin_amdgcn_global_load_lds( \
    (const __attribute__((address_space(1))) void*)(g),   \
    (__attribute__((address_space(3))) void*)(l), 16, 0, 0)

// ---------------- generic f16 MFMA GEMM: C[M,N] = A[M,K] @ B[N,K]^T ----------------
template<int EPI>
__global__ __launch_bounds__(256) void gemm_f16(
    const _Float16* __restrict__ A, const _Float16* __restrict__ B,
    float* __restrict__ Cf, _Float16* __restrict__ Ch,
    const float* __restrict__ bias, int N, int K, int ldc, int ntm)
{
  __shared__ char smem[32768];
  _Float16* Al = (_Float16*)smem;
  _Float16* Bl = (_Float16*)(smem + 16384);
  int bid = blockIdx.x;
  int bm = bid % ntm, bn = bid / ntm;
  int t = threadIdx.x;
  int w = t >> 6, l = t & 63;

  floatx4 acc[4][4];
#pragma unroll
  for (int i = 0; i < 4; ++i)
#pragma unroll
    for (int j = 0; j < 4; ++j) acc[i][j] = (floatx4){0.f, 0.f, 0.f, 0.f};

  const char* Ab = (const char*)A + (size_t)bm * 128 * K * 2;
  const char* Bb = (const char*)B + (size_t)bn * 128 * K * 2;
  const int rowb = K * 2;
  const int r0 = t >> 3;
  const int cbyte = ((t & 7) * 16) ^ (((t >> 3) & 7) << 4);
  char* AlB = (char*)Al;
  char* BlB = (char*)Bl;
  const int wm = (w >> 1) * 64, wn = (w & 1) * 64;

  for (int kt = 0; kt < K; kt += 64) {
    __syncthreads();
#pragma unroll
    for (int c = 0; c < 4; ++c) {
      int row = c * 32 + r0;
      GLD_LDS16(Ab + (size_t)row * rowb + kt * 2 + cbyte, AlB + c * 4096 + t * 16);
      GLD_LDS16(Bb + (size_t)row * rowb + kt * 2 + cbyte, BlB + c * 4096 + t * 16);
    }
    __syncthreads();
#pragma unroll
    for (int kk = 0; kk < 64; kk += 32) {
      h8 af[4], bfv[4];
#pragma unroll
      for (int i = 0; i < 4; ++i) {
        int ra = wm + i * 16 + (l & 15);
        int cb = ((kk << 1) + ((l >> 4) << 4)) ^ ((ra & 7) << 4);
        af[i] = *(const h8*)(AlB + ra * 128 + cb);
      }
#pragma unroll
      for (int j = 0; j < 4; ++j) {
        int ra = wn + j * 16 + (l & 15);
        int cb = ((kk << 1) + ((l >> 4) << 4)) ^ ((ra & 7) << 4);
        bfv[j] = *(const h8*)(BlB + ra * 128 + cb);
      }
#pragma unroll
      for (int i = 0; i < 4; ++i)
#pragma unroll
        for (int j = 0; j < 4; ++j)
          acc[i][j] = __builtin_amdgcn_mfma_f32_16x16x32_f16(af[i], bfv[j], acc[i][j], 0, 0, 0);
    }
  }

  if (EPI == 3) {
    // staged epilogue: full-line coalesced fp32 writes
    float* Cs = (float*)smem;   // 64 rows x 128 cols fp32 = 32 KB
#pragma unroll
    for (int half = 0; half < 2; ++half) {
      __syncthreads();
      if ((w >> 1) == half) {
        int rbase = ((l >> 4) << 2);
#pragma unroll
        for (int i = 0; i < 4; ++i)
#pragma unroll
          for (int j = 0; j < 4; ++j)
#pragma unroll
            for (int r = 0; r < 4; ++r)
              Cs[(i * 16 + rbase + r) * 128 + wn + j * 16 + (l & 15)] = acc[i][j][r];
      }
      __syncthreads();
#pragma unroll
      for (int rr = 0; rr < 16; ++rr) {
        int row = rr * 4 + w;
        int grow = bm * 128 + half * 64 + row;
        int cc = bn * 128 + 2 * l;
        float2 v = *(float2*)&Cs[row * 128 + 2 * l];
        float vv0, vv1;
        if (cc < N)     { float x0 = v.x + bias[cc];     vv0 = (x0 == 0.f) ? -NEGF : x0; } else vv0 = -NEGF;
        if (cc + 1 < N) { float x1 = v.y + bias[cc + 1]; vv1 = (x1 == 0.f) ? -NEGF : x1; } else vv1 = -NEGF;
        float* orow = Cf + (size_t)grow * ldc;
        if (cc + 1 < ldc) { float2 o; o.x = vv0; o.y = vv1; *(float2*)(orow + cc) = o; }
        else if (cc < ldc) orow[cc] = vv0;
      }
    }
  } else {
    int mbase = bm * 128 + wm + ((l >> 4) << 2);
    int nbase = bn * 128 + wn + (l & 15);
#pragma unroll
    for (int j = 0; j < 4; ++j) {
      int col = nbase + j * 16;
#pragma unroll
      for (int i = 0; i < 4; ++i) {
#pragma unroll
        for (int r = 0; r < 4; ++r) {
          int row = mbase + i * 16 + r;
          float v = acc[i][j][r];
          if (col < N) {
            float bv = bias ? bias[col] : 0.f;
            if (EPI == 0)      Cf[(size_t)row * ldc + col] = v + bv;
            else if (EPI == 1) Ch[(size_t)row * ldc + col] = (_Float16)(v + bv);
            else               Ch[(size_t)row * ldc + col] = (_Float16)tanhf(v + bv);
          }
        }
      }
    }
  }
}

// ---------------- cast / pad kernels ----------------
__global__ void cast_pad_kernel(const float* __restrict__ src, _Float16* __restrict__ dst,
                                int R, int C, int ld_src, int Cpad, int ld_dst, long total){
  long i = (long)blockIdx.x * 256 + threadIdx.x;
  if (i >= total) return;
  int r = (int)(i / Cpad), c = (int)(i % Cpad);
  float v = (r < R && c < C) ? src[(size_t)r * ld_src + c] : 0.f;
  dst[(size_t)r * ld_dst + c] = (_Float16)v;
}

__global__ void cast_emb_kernel(const float* __restrict__ trg, _Float16* __restrict__ dst){
  int i = blockIdx.x * 256 + threadIdx.x;
  if (i >= 1024 * 320) return;
  int m = i / 320, e = i % 320;
  int tt = m >> 5, b = m & 31;
  float v = (e < 300) ? trg[((size_t)b * 32 + tt) * 300 + e] : 0.f;
  dst[i] = (_Float16)v;
}

__global__ void cast_wr2t_kernel(const float* __restrict__ wred, _Float16* __restrict__ dst){
  int i = blockIdx.x * 256 + threadIdx.x;
  if (i >= 512 * 320) return;
  int h = i / 320, e = i % 320;
  float v = (e < 300) ? wred[(size_t)e * 812 + 300 + h] : 0.f;
  dst[i] = (_Float16)v;
}

__global__ void init_kernel(const float* __restrict__ h0, const float* __restrict__ b_ih,
                            const float* __restrict__ b_hh,
                            _Float16* __restrict__ HCz, float* __restrict__ bias_sum,
                            _Float16* __restrict__ X1h, unsigned* __restrict__ bar){
  int i = blockIdx.x * 256 + threadIdx.x;
  if (i < 32768) {  // HCz row 0 = [h0 | 0]
    int b = i >> 10, k = i & 1023;
    HCz[i] = (k < 512) ? (_Float16)h0[b * 512 + k] : (_Float16)0.f;
  }
  if (i < 2048)  bias_sum[i] = b_ih[i] + b_hh[i];
  if (i < 327680) X1h[i] = (_Float16)0.f;
  if (i < 2) bar[i] = 0u;
}

// ---------------- grid barrier (agent-scope, sense via generation counter) ----------------
__device__ __forceinline__ void gbar(unsigned* bar, unsigned nb){
  __syncthreads();
  if (threadIdx.x == 0) {
    __builtin_amdgcn_fence(__ATOMIC_RELEASE, "agent");
    unsigned g = __hip_atomic_load(bar + 1, __ATOMIC_RELAXED, __HIP_MEMORY_SCOPE_AGENT);
    unsigned a = __hip_atomic_fetch_add(bar, 1u, __ATOMIC_ACQ_REL, __HIP_MEMORY_SCOPE_AGENT);
    if (a == nb - 1u) {
      __hip_atomic_store(bar, 0u, __ATOMIC_RELAXED, __HIP_MEMORY_SCOPE_AGENT);
      __hip_atomic_store(bar + 1, g + 1u, __ATOMIC_RELEASE, __HIP_MEMORY_SCOPE_AGENT);
    } else {
      while (__hip_atomic_load(bar + 1, __ATOMIC_RELAXED, __HIP_MEMORY_SCOPE_AGENT) == g)
        __builtin_amdgcn_s_sleep(2);
    }
    __builtin_amdgcn_fence(__ATOMIC_ACQUIRE, "agent");
  }
  __syncthreads();
}

// ---------------- fused persistent recurrence: 32 blocks x 512 threads ----------------
// Per step: phase A: gates = P + z@Wz^T (MFMA, weights in regs), LSTM pointwise (c in reg)
//           phase B: block b: energy/softmax/context for batch b
__global__ __launch_bounds__(512) void fused_loop(
    const _Float16* __restrict__ memh, _Float16* __restrict__ HCz,
    const _Float16* __restrict__ Wz, const float* __restrict__ P,
    const float* __restrict__ inits, const int* __restrict__ mask,
    float* __restrict__ e_out, float* __restrict__ a_out, unsigned* bar)
{
  __shared__ _Float16 Zl[32768];   // 64 KB, 16B unit (b*4+q)*32 + (ks^b)
  __shared__ float gl[2048];       // gates [b][r] 8 KB
  __shared__ float es[400];
  __shared__ float red[16];

  const int blk = blockIdx.x, t = threadIdx.x;
  const int w = t >> 6, l = t & 63;
  const int ri = w & 3, bi = w >> 2;
  const int pb = t >> 4, pj = t & 15;

  // preload weight B-fragments: wave ri covers gate type ri, rows blk*16+(l&15)
  h8 wf[32];
  {
    const _Float16* wrow = Wz + ((size_t)(ri * 512 + blk * 16 + (l & 15))) * 1024 + ((l >> 4) << 3);
#pragma unroll
    for (int ks = 0; ks < 32; ++ks) wf[ks] = *(const h8*)(wrow + ks * 32);
  }
  float creg = inits[pb * 512 + blk * 16 + pj];   // c0 = h0

  for (int ts = 0; ts < 32; ++ts) {
    // ---- phase A: stage z into swizzled LDS ----
    const char* zsrc = (const char*)(HCz + (size_t)ts * 32768);
#pragma unroll
    for (int it = 0; it < 8; ++it) {
      int m = it * 512 + t;
      int b = m >> 7, ksx = m & 31, q = (m >> 5) & 3;
      int srcu = b * 128 + ((ksx ^ b) << 2) + q;
      GLD_LDS16(zsrc + (size_t)srcu * 16, (char*)Zl + (size_t)m * 16);
    }
    __syncthreads();
    // gates MFMA: C tile [16b x 16r] per wave
    floatx4 acc = (floatx4){0.f, 0.f, 0.f, 0.f};
    {
      int b = bi * 16 + (l & 15);
      int q = l >> 4;
#pragma unroll
      for (int ks = 0; ks < 32; ++ks) {
        int unit = (b * 4 + q) * 32 + (ks ^ b);
        h8 af = *(const h8*)((char*)Zl + (size_t)unit * 16);
        acc = __builtin_amdgcn_mfma_f32_16x16x32_f16(af, wf[ks], acc, 0, 0, 0);
      }
    }
    {
      int gb = bi * 16 + ((l >> 4) << 2);
      int gr = ri * 16 + (l & 15);
#pragma unroll
      for (int r2 = 0; r2 < 4; ++r2) gl[(gb + r2) * 64 + gr] = acc[r2];
    }
    __syncthreads();
    // pointwise LSTM for (pb, pj)
    {
      const float* Pr = P + ((size_t)ts * 32 + pb) * 2048 + blk * 16 + pj;
      float gi = gl[pb * 64 + pj]      + Pr[0];
      float gf = gl[pb * 64 + 16 + pj] + Pr[512];
      float gg = gl[pb * 64 + 32 + pj] + Pr[1024];
      float go = gl[pb * 64 + 48 + pj] + Pr[1536];
      float ig = 1.f / (1.f + expf(-gi));
      float fg = 1.f / (1.f + expf(-gf));
      float og = 1.f / (1.f + expf(-go));
      float cn = fg * creg + ig * tanhf(gg);
      float hn = og * tanhf(cn);
      creg = cn;
      unsigned hu = (unsigned)f16bits(hn);
      unsigned other = __shfl_xor(hu, 1);
      if (!(pj & 1)) {
        unsigned pack = hu | (other << 16);
        *(unsigned*)((char*)HCz + ((size_t)(ts + 1) * 32768 + (size_t)pb * 1024 + blk * 16 + pj) * 2) = pack;
      }
    }
    gbar(bar, 32);

    // ---- phase B: attention for batch blk ----
    {
      const _Float16* hrow = HCz + (size_t)(ts + 1) * 32768 + (size_t)blk * 1024;
      const _Float16* mb = memh + (size_t)blk * 400 * 512;
      size_t obase = (size_t)ts * 12800 + blk * 400;
      h8 hv = *(const h8*)(hrow + l * 8);
      for (int r = 0; r < 50; ++r) {
        int s = w * 50 + r;
        h8 mv = *(const h8*)(mb + (size_t)s * 512 + l * 8);
        float e = dot8(mv, hv, 0.f);
#pragma unroll
        for (int o = 32; o; o >>= 1) e += __shfl_xor(e, o);
        if (l == 0) {
          if (mask[blk * 400 + s] == 0) e = -NEGF;
          es[s] = e;
          e_out[obase + s] = e;
        }
      }
      __syncthreads();
      float v = (t < 400) ? es[t] : -3.4e38f;
      float m = v;
#pragma unroll
      for (int o = 32; o; o >>= 1) m = fmaxf(m, __shfl_xor(m, o));
      if (l == 0) red[w] = m;
      __syncthreads();
      m = red[0];
#pragma unroll
      for (int q = 1; q < 8; ++q) m = fmaxf(m, red[q]);
      float p = (t < 400) ? expf(v - m) : 0.f;
      if (t < 400) es[t] = p;
      float sum = p;
#pragma unroll
      for (int o = 32; o; o >>= 1) sum += __shfl_xor(sum, o);
      if (l == 0) red[8 + w] = sum;
      __syncthreads();
      float tot = red[8];
#pragma unroll
      for (int q = 9; q < 16; ++q) tot += red[q];
      float inv = 1.f / tot;
      if (t < 400) a_out[obase + t] = p * inv;
      __syncthreads();
      float acc2 = 0.f;
#pragma unroll 4
      for (int s = 0; s < 400; ++s)
        acc2 += es[s] * (float)mb[(size_t)s * 512 + t];
      unsigned cu = (unsigned)f16bits(acc2 * inv);
      unsigned other = __shfl_xor(cu, 1);
      if (!(t & 1)) {
        unsigned pack = cu | (other << 16);
        *(unsigned*)((char*)HCz + ((size_t)(ts + 1) * 32768 + (size_t)blk * 1024 + 512 + t) * 2) = pack;
      }
    }
    gbar(bar, 32);
  }
}

// ---------------- coverage ----------------
__global__ void cov_kernel(const float* __restrict__ attn, float* __restrict__ cov){
  int idx = blockIdx.x * 256 + threadIdx.x;
  if (idx >= 12800) return;
  float acc = 0.f;
  for (int t = 0; t < 32; ++t) {
    cov[(size_t)t * 12800 + idx] = acc;
    acc += attn[(size_t)t * 12800 + idx];
  }
}

// ---------------- pointer scatter-max patch ----------------
__global__ __launch_bounds__(512) void pointer_kernel(
    const int* __restrict__ ext, const float* __restrict__ energ, float* __restrict__ logits)
{
  __shared__ int ids[400];
  __shared__ float es[400];
  int tb = blockIdx.x;
  int b = tb & 31;
  int tt = tb >> 5;
  int t = threadIdx.x;
  if (t < 400) {
    ids[t] = ext[b * 400 + t];
    es[t] = energ[(size_t)tt * 12800 + b * 400 + t];
  }
  __syncthreads();
  if (t < 400) {
    int id = ids[t];
    bool first = true;
    for (int s = 0; s < t; ++s) if (ids[s] == id) { first = false; break; }
    if (first) {
      float mx = es[t];
      for (int s = t + 1; s < 400; ++s) if (ids[s] == id) mx = fmaxf(mx, es[s]);
      if (mx != -NEGF) {
        float* p = &logits[(size_t)tb * 45050 + id];
        float base = 0.f;
        if (id < 45000) { float cur = *p; base = (cur == -NEGF) ? 0.f : cur; }
        float nv = base + mx;
        *p = (nv == 0.f) ? -NEGF : nv;
      }
    }
  }
}

// ---------------- host launcher ----------------
extern "C" void kernel_launch(void* const* d_in, const int* in_sizes, int n_in,
                              void* d_out, int out_size, void* d_ws, size_t ws_size,
                              hipStream_t stream) {
  const float* trg   = (const float*)d_in[0];
  const int*   ext   = (const int*)d_in[1];
  const float* inits = (const float*)d_in[2];
  const float* enc   = (const float*)d_in[3];
  const int*   mask  = (const int*)d_in[4];
  const float* W_enc = (const float*)d_in[5];
  const float* b_enc = (const float*)d_in[6];
  const float* W_red = (const float*)d_in[7];
  const float* b_red = (const float*)d_in[8];
  const float* W_ih  = (const float*)d_in[9];
  const float* W_hh  = (const float*)d_in[10];
  const float* b_ih  = (const float*)d_in[11];
  const float* b_hh  = (const float*)d_in[12];
  const float* W_cat = (const float*)d_in[13];
  const float* b_cat = (const float*)d_in[14];
  const float* W_log = (const float*)d_in[15];
  const float* b_log = (const float*)d_in[16];

  float* out = (float*)d_out;
  float* out_logits = out;                       // [1024 x 45050]
  float* out_attn   = out + 46131200;
  float* out_cov    = out_attn + 409600;
  float* out_energy = out_cov + 409600;

  char* ws = (char*)d_ws;
  size_t o = 0;
  auto alloc = [&](size_t bytes) { void* p = ws + o; o += (bytes + 255) & ~(size_t)255; return p; };
  _Float16* mem_h   = (_Float16*)alloc(12800ULL * 512 * 2);
  _Float16* enc_h   = (_Float16*)alloc(12800ULL * 512 * 2);
  _Float16* W_enc_h = (_Float16*)alloc(512ULL * 512 * 2);
  _Float16* emb_h   = (_Float16*)alloc(1024ULL * 320 * 2);
  _Float16* Wr1_h   = (_Float16*)alloc(384ULL * 320 * 2);
  _Float16* X1_h    = (_Float16*)alloc(1024ULL * 320 * 2);
  _Float16* W_ih_h  = (_Float16*)alloc(2048ULL * 320 * 2);
  _Float16* Wr2T_h  = (_Float16*)alloc(512ULL * 320 * 2);
  _Float16* W_cat_h = (_Float16*)alloc(512ULL * 1024 * 2);
  _Float16* W_log_h = (_Float16*)alloc(45056ULL * 512 * 2);
  _Float16* A_log_h = (_Float16*)alloc(1024ULL * 512 * 2);
  _Float16* HCz     = (_Float16*)alloc(33ULL * 32768 * 2);
  _Float16* Wz      = (_Float16*)alloc(2048ULL * 1024 * 2); // [Whh | M1]
  float* P        = (float*)alloc(1024ULL * 2048 * 4);
  float* bias_sum = (float*)alloc(2048ULL * 4);
  unsigned* bar   = (unsigned*)alloc(256);

  auto blocks = [](long total) { return (int)((total + 255) / 256); };

  // init + casts
  init_kernel<<<blocks(327680), 256, 0, stream>>>(inits, b_ih, b_hh, HCz, bias_sum, X1_h, bar);
  cast_pad_kernel<<<blocks(12800L*512), 256, 0, stream>>>(enc,   enc_h,   12800, 512, 512, 512, 512, 12800L*512);
  cast_pad_kernel<<<blocks(512L*512),   256, 0, stream>>>(W_enc, W_enc_h, 512,   512, 512, 512, 512, 512L*512);
  cast_pad_kernel<<<blocks(384L*320),   256, 0, stream>>>(W_red, Wr1_h,   300,   300, 812, 320, 320, 384L*320);
  cast_pad_kernel<<<blocks(2048L*320),  256, 0, stream>>>(W_ih,  W_ih_h,  2048,  300, 300, 320, 320, 2048L*320);
  cast_pad_kernel<<<blocks(512L*1024),  256, 0, stream>>>(W_cat, W_cat_h, 512,  1024, 1024, 1024, 1024, 512L*1024);
  cast_pad_kernel<<<blocks(45056L*512), 256, 0, stream>>>(W_log, W_log_h, 45000, 512, 512, 512, 512, 45056L*512);
  cast_pad_kernel<<<blocks(2048L*512),  256, 0, stream>>>(W_hh,  Wz,      2048,  512, 512, 512, 1024, 2048L*512);
  cast_emb_kernel<<<blocks(1024L*320), 256, 0, stream>>>(trg, emb_h);
  cast_wr2t_kernel<<<blocks(512L*320), 256, 0, stream>>>(W_red, Wr2T_h);

  // batched pre-GEMMs
  gemm_f16<1><<<400, 256, 0, stream>>>(enc_h, W_enc_h, nullptr, mem_h, b_enc, 512, 512, 512, 100);
  gemm_f16<1><<<24,  256, 0, stream>>>(emb_h, Wr1_h, nullptr, X1_h, b_red, 300, 320, 320, 8);
  gemm_f16<0><<<128, 256, 0, stream>>>(X1_h, W_ih_h, P, nullptr, bias_sum, 2048, 320, 2048, 8);
  gemm_f16<1><<<64,  256, 0, stream>>>(W_ih_h, Wr2T_h, nullptr, Wz + 512, nullptr, 512, 320, 1024, 16);

  // fused persistent recurrence (one launch for all 32 steps)
  fused_loop<<<32, 512, 0, stream>>>(mem_h, HCz, Wz, P, inits, mask, out_energy, out_attn, bar);

  // epilogue
  cov_kernel<<<50, 256, 0, stream>>>(out_attn, out_cov);
  gemm_f16<2><<<32, 256, 0, stream>>>(HCz + 32768, W_cat_h, nullptr, A_log_h, b_cat, 512, 1024, 512, 8);
  gemm_f16<3><<<2816, 256, 0, stream>>>(A_log_h, W_log_h, out_logits, nullptr, b_log, 45000, 512, 45050, 8);
  pointer_kernel<<<1024, 512, 0, stream>>>(ext, out_energy, out_logits);
}

// Round 5
// 1664.664 us; speedup vs baseline: 1.6428x; 1.1125x over previous
//
#include <hip/hip_runtime.h>
#include <hip/hip_bf16.h>

typedef _Float16 h2 __attribute__((ext_vector_type(2)));
typedef _Float16 h8 __attribute__((ext_vector_type(8)));
typedef __attribute__((ext_vector_type(4))) float floatx4;

#define NEGF 1.0e12f

#if __has_builtin(__builtin_amdgcn_fdot2)
#define DOT2(a,b,c) __builtin_amdgcn_fdot2((a),(b),(c),false)
#else
static __device__ __forceinline__ float DOT2(h2 a, h2 b, float c){
  return c + (float)a[0]*(float)b[0] + (float)a[1]*(float)b[1];
}
#endif

__device__ __forceinline__ float dot8(h8 a, h8 b, float c){
  h2 a0 = {a[0],a[1]}, a1 = {a[2],a[3]}, a2 = {a[4],a[5]}, a3 = {a[6],a[7]};
  h2 b0 = {b[0],b[1]}, b1 = {b[2],b[3]}, b2 = {b[4],b[5]}, b3 = {b[6],b[7]};
  c = DOT2(a0,b0,c); c = DOT2(a1,b1,c); c = DOT2(a2,b2,c); c = DOT2(a3,b3,c);
  return c;
}

__device__ __forceinline__ unsigned f16bits(float x){
  union { _Float16 h; unsigned short u; } cv; cv.h = (_Float16)x; return (unsigned)cv.u;
}

#define GLD_LDS16(g, l) __builtin_amdgcn_global_load_lds( \
    (const __attribute__((address_space(1))) void*)(g),   \
    (__attribute__((address_space(3))) void*)(l), 16, 0, 0)

#define ALOAD64(p)    __hip_atomic_load((p), __ATOMIC_RELAXED, __HIP_MEMORY_SCOPE_AGENT)
#define ASTORE32(p,v) __hip_atomic_store((p), (v), __ATOMIC_RELAXED, __HIP_MEMORY_SCOPE_AGENT)

// ---------------- generic f16 MFMA GEMM: C[M,N] = A[M,K] @ B[N,K]^T ----------------
template<int EPI>
__global__ __launch_bounds__(256) void gemm_f16(
    const _Float16* __restrict__ A, const _Float16* __restrict__ B,
    float* __restrict__ Cf, _Float16* __restrict__ Ch,
    const float* __restrict__ bias, int N, int K, int ldc, int ntm)
{
  __shared__ char smem[32768];
  _Float16* Al = (_Float16*)smem;
  _Float16* Bl = (_Float16*)(smem + 16384);
  int bid = blockIdx.x;
  int bm = bid % ntm, bn = bid / ntm;
  int t = threadIdx.x;
  int w = t >> 6, l = t & 63;

  floatx4 acc[4][4];
#pragma unroll
  for (int i = 0; i < 4; ++i)
#pragma unroll
    for (int j = 0; j < 4; ++j) acc[i][j] = (floatx4){0.f, 0.f, 0.f, 0.f};

  const char* Ab = (const char*)A + (size_t)bm * 128 * K * 2;
  const char* Bb = (const char*)B + (size_t)bn * 128 * K * 2;
  const int rowb = K * 2;
  const int r0 = t >> 3;
  const int cbyte = ((t & 7) * 16) ^ (((t >> 3) & 7) << 4);
  char* AlB = (char*)Al;
  char* BlB = (char*)Bl;
  const int wm = (w >> 1) * 64, wn = (w & 1) * 64;

  for (int kt = 0; kt < K; kt += 64) {
    __syncthreads();
#pragma unroll
    for (int c = 0; c < 4; ++c) {
      int row = c * 32 + r0;
      GLD_LDS16(Ab + (size_t)row * rowb + kt * 2 + cbyte, AlB + c * 4096 + t * 16);
      GLD_LDS16(Bb + (size_t)row * rowb + kt * 2 + cbyte, BlB + c * 4096 + t * 16);
    }
    __syncthreads();
#pragma unroll
    for (int kk = 0; kk < 64; kk += 32) {
      h8 af[4], bfv[4];
#pragma unroll
      for (int i = 0; i < 4; ++i) {
        int ra = wm + i * 16 + (l & 15);
        int cb = ((kk << 1) + ((l >> 4) << 4)) ^ ((ra & 7) << 4);
        af[i] = *(const h8*)(AlB + ra * 128 + cb);
      }
#pragma unroll
      for (int j = 0; j < 4; ++j) {
        int ra = wn + j * 16 + (l & 15);
        int cb = ((kk << 1) + ((l >> 4) << 4)) ^ ((ra & 7) << 4);
        bfv[j] = *(const h8*)(BlB + ra * 128 + cb);
      }
#pragma unroll
      for (int i = 0; i < 4; ++i)
#pragma unroll
        for (int j = 0; j < 4; ++j)
          acc[i][j] = __builtin_amdgcn_mfma_f32_16x16x32_f16(af[i], bfv[j], acc[i][j], 0, 0, 0);
    }
  }

  if (EPI == 3) {
    float* Cs = (float*)smem;
#pragma unroll
    for (int half = 0; half < 2; ++half) {
      __syncthreads();
      if ((w >> 1) == half) {
        int rbase = ((l >> 4) << 2);
#pragma unroll
        for (int i = 0; i < 4; ++i)
#pragma unroll
          for (int j = 0; j < 4; ++j)
#pragma unroll
            for (int r = 0; r < 4; ++r)
              Cs[(i * 16 + rbase + r) * 128 + wn + j * 16 + (l & 15)] = acc[i][j][r];
      }
      __syncthreads();
#pragma unroll
      for (int rr = 0; rr < 16; ++rr) {
        int row = rr * 4 + w;
        int grow = bm * 128 + half * 64 + row;
        int cc = bn * 128 + 2 * l;
        float2 v = *(float2*)&Cs[row * 128 + 2 * l];
        float vv0, vv1;
        if (cc < N)     { float x0 = v.x + bias[cc];     vv0 = (x0 == 0.f) ? -NEGF : x0; } else vv0 = -NEGF;
        if (cc + 1 < N) { float x1 = v.y + bias[cc + 1]; vv1 = (x1 == 0.f) ? -NEGF : x1; } else vv1 = -NEGF;
        float* orow = Cf + (size_t)grow * ldc;
        if (cc + 1 < ldc) { float2 o; o.x = vv0; o.y = vv1; *(float2*)(orow + cc) = o; }
        else if (cc < ldc) orow[cc] = vv0;
      }
    }
  } else {
    int mbase = bm * 128 + wm + ((l >> 4) << 2);
    int nbase = bn * 128 + wn + (l & 15);
#pragma unroll
    for (int j = 0; j < 4; ++j) {
      int col = nbase + j * 16;
#pragma unroll
      for (int i = 0; i < 4; ++i) {
#pragma unroll
        for (int r = 0; r < 4; ++r) {
          int row = mbase + i * 16 + r;
          float v = acc[i][j][r];
          if (col < N) {
            float bv = bias ? bias[col] : 0.f;
            if (EPI == 0)      Cf[(size_t)row * ldc + col] = v + bv;
            else if (EPI == 1) Ch[(size_t)row * ldc + col] = (_Float16)(v + bv);
            else               Ch[(size_t)row * ldc + col] = (_Float16)tanhf(v + bv);
          }
        }
      }
    }
  }
}

// ---------------- cast / pad kernels ----------------
__global__ void cast_pad_kernel(const float* __restrict__ src, _Float16* __restrict__ dst,
                                int R, int C, int ld_src, int Cpad, int ld_dst, long total){
  long i = (long)blockIdx.x * 256 + threadIdx.x;
  if (i >= total) return;
  int r = (int)(i / Cpad), c = (int)(i % Cpad);
  float v = (r < R && c < C) ? src[(size_t)r * ld_src + c] : 0.f;
  dst[(size_t)r * ld_dst + c] = (_Float16)v;
}

__global__ void cast_emb_kernel(const float* __restrict__ trg, _Float16* __restrict__ dst){
  int i = blockIdx.x * 256 + threadIdx.x;
  if (i >= 1024 * 320) return;
  int m = i / 320, e = i % 320;
  int tt = m >> 5, b = m & 31;
  float v = (e < 300) ? trg[((size_t)b * 32 + tt) * 300 + e] : 0.f;
  dst[i] = (_Float16)v;
}

__global__ void cast_wr2t_kernel(const float* __restrict__ wred, _Float16* __restrict__ dst){
  int i = blockIdx.x * 256 + threadIdx.x;
  if (i >= 512 * 320) return;
  int h = i / 320, e = i % 320;
  float v = (e < 300) ? wred[(size_t)e * 812 + 300 + h] : 0.f;
  dst[i] = (_Float16)v;
}

// HCzT slab layout: 128 units/kc-row? unit = kc*32 + b (kc in [0,128), b in [0,32)), 8 halves each.
// half index i: unit = i>>3, pos = i&7, k = kc*8+pos; k<512 -> h, else ctx.
__global__ void init_kernel(const float* __restrict__ h0, const float* __restrict__ b_ih,
                            const float* __restrict__ b_hh,
                            _Float16* __restrict__ HCzT, float* __restrict__ bias_sum,
                            _Float16* __restrict__ X1h, unsigned* __restrict__ bar){
  int i = blockIdx.x * 256 + threadIdx.x;
  if (i < 32768) {
    int unit = i >> 3, pos = i & 7;
    int kc = unit >> 5, b = unit & 31;
    int k = kc * 8 + pos;
    HCzT[i] = (k < 512) ? (_Float16)h0[b * 512 + k] : (_Float16)0.f;
  }
  if (i < 2048)  bias_sum[i] = b_ih[i] + b_hh[i];
  if (i < 327680) X1h[i] = (_Float16)0.f;
  if (i < 1024) bar[i] = 0u;
}

// ---------------- fence-free flag barrier ----------------
__device__ __forceinline__ void gbar(unsigned* cnt){
  asm volatile("s_waitcnt vmcnt(0)" ::: "memory");   // every wave drains its bypass stores
  __syncthreads();
  if (threadIdx.x == 0) {
    __hip_atomic_fetch_add(cnt, 1u, __ATOMIC_RELAXED, __HIP_MEMORY_SCOPE_AGENT);
    while (__hip_atomic_load(cnt, __ATOMIC_RELAXED, __HIP_MEMORY_SCOPE_AGENT) < 32u)
      __builtin_amdgcn_s_sleep(1);
  }
  __syncthreads();
  asm volatile("" ::: "memory");
}

// ---------------- fused persistent recurrence: 32 blocks x 512 threads ----------------
// Block q: gates j-slice [q*16, q*16+16) for ALL batches (weights in 128 VGPRs of B-frags),
//          attention for batch q. Cross-block h/ctx exchange via relaxed agent atomics
//          on transposed HCzT; NO fences -> mem_h/Wz/P stay L2-resident.
__global__ __launch_bounds__(512, 2) void fused_loop(
    const _Float16* __restrict__ memh, _Float16* __restrict__ HCzT,
    _Float16* __restrict__ HC_A, const _Float16* __restrict__ Wz,
    const float* __restrict__ P, const float* __restrict__ inits,
    const int* __restrict__ mask, float* __restrict__ e_out,
    float* __restrict__ a_out, unsigned* __restrict__ bar)
{
  __shared__ float gl[8192];     // [ (s*4+nw) ][512]  partial gate sums, 32 KB
  __shared__ float es[400];
  __shared__ float red[16];

  const int q = blockIdx.x, t = threadIdx.x;
  const int w = t >> 6, l = t & 63;
  const int mw = w >> 2, nw = w & 3;    // m-half (batches), k-quarter

  // preload B-frags: wf[s*8+kk8] = Wz[s*512 + q*16 + (l&15)][(nw*8+kk8)*32 + (l>>4)*8 ..+8]
  h8 wf[32];
#pragma unroll
  for (int s = 0; s < 4; ++s) {
    const _Float16* wrow = Wz + (size_t)(s * 512 + q * 16 + (l & 15)) * 1024 + ((l >> 4) << 3);
#pragma unroll
    for (int kk8 = 0; kk8 < 8; ++kk8)
      wf[s * 8 + kk8] = *(const h8*)(wrow + (nw * 8 + kk8) * 32);
  }

  float creg = inits[(t >> 4) * 512 + q * 16 + (t & 15)];   // c0 = h0
  const _Float16* mb = memh + (size_t)q * 400 * 512;

  for (int ts = 0; ts < 32; ++ts) {
    // ---- phase A: gates MFMA (A = z via bypass loads, B = register frags) ----
    {
      unsigned long long* zsrc = (unsigned long long*)(HCzT + (size_t)ts * 32768);
      floatx4 acc[4];
#pragma unroll
      for (int s = 0; s < 4; ++s) acc[s] = (floatx4){0.f, 0.f, 0.f, 0.f};
#pragma unroll
      for (int kk8 = 0; kk8 < 8; ++kk8) {
        int unit = ((nw * 8 + kk8) * 4 + (l >> 4)) * 32 + mw * 16 + (l & 15);
        union { unsigned long long u[2]; h8 v; } za;
        za.u[0] = ALOAD64(zsrc + (size_t)unit * 2);
        za.u[1] = ALOAD64(zsrc + (size_t)unit * 2 + 1);
#pragma unroll
        for (int s = 0; s < 4; ++s)
          acc[s] = __builtin_amdgcn_mfma_f32_16x16x32_f16(za.v, wf[s * 8 + kk8], acc[s], 0, 0, 0);
      }
#pragma unroll
      for (int s = 0; s < 4; ++s)
#pragma unroll
        for (int r = 0; r < 4; ++r) {
          int b = mw * 16 + ((l >> 4) << 2) + r;
          gl[(s * 4 + nw) * 512 + b * 16 + (l & 15)] = acc[s][r];
        }
    }
    __syncthreads();
    // ---- LSTM pointwise: thread t -> (b = t>>4, j16 = t&15) ----
    {
      int b = t >> 4, j16 = t & 15;
      const float* Pr = P + ((size_t)ts * 32 + b) * 2048 + q * 16 + j16;
      float g4[4];
#pragma unroll
      for (int s = 0; s < 4; ++s)
        g4[s] = gl[(s * 4 + 0) * 512 + t] + gl[(s * 4 + 1) * 512 + t]
              + gl[(s * 4 + 2) * 512 + t] + gl[(s * 4 + 3) * 512 + t] + Pr[s * 512];
      float ig = 1.f / (1.f + expf(-g4[0]));
      float fg = 1.f / (1.f + expf(-g4[1]));
      float og = 1.f / (1.f + expf(-g4[3]));
      float cn = fg * creg + ig * tanhf(g4[2]);
      float hn = og * tanhf(cn);
      creg = cn;
      unsigned hu = f16bits(hn);
      unsigned other = __shfl_xor(hu, 1);
      if (!(t & 1)) {
        unsigned pack = hu | (other << 16);
        int j = q * 16 + j16;   // even
        unsigned* dst = (unsigned*)((char*)(HCzT + (size_t)(ts + 1) * 32768)
                                    + (((j >> 3) * 32 + b) << 4) + ((j & 7) << 1));
        ASTORE32(dst, pack);
        *(unsigned*)(HC_A + ((size_t)ts * 32 + b) * 1024 + j) = pack;   // normal store for epilogue
      }
    }
    gbar(bar + ts * 32);

    // ---- phase B: attention for batch q ----
    {
      unsigned long long* hsrc = (unsigned long long*)(HCzT + (size_t)(ts + 1) * 32768);
      union { unsigned long long u[2]; h8 v; } ha;
      ha.u[0] = ALOAD64(hsrc + ((size_t)l * 32 + q) * 2);
      ha.u[1] = ALOAD64(hsrc + ((size_t)l * 32 + q) * 2 + 1);
      size_t obase = (size_t)ts * 12800 + q * 400;
      for (int r = 0; r < 50; ++r) {
        int s = w * 50 + r;
        h8 mv = *(const h8*)(mb + (size_t)s * 512 + l * 8);
        float e = dot8(mv, ha.v, 0.f);
#pragma unroll
        for (int o = 32; o; o >>= 1) e += __shfl_xor(e, o);
        if (l == 0) {
          if (mask[q * 400 + s] == 0) e = -NEGF;
          es[s] = e;
          e_out[obase + s] = e;
        }
      }
      __syncthreads();
      float v = (t < 400) ? es[t] : -3.4e38f;
      float m = v;
#pragma unroll
      for (int o = 32; o; o >>= 1) m = fmaxf(m, __shfl_xor(m, o));
      if (l == 0) red[w] = m;
      __syncthreads();
      m = red[0];
#pragma unroll
      for (int qq = 1; qq < 8; ++qq) m = fmaxf(m, red[qq]);
      float p = (t < 400) ? expf(v - m) : 0.f;
      if (t < 400) es[t] = p;
      float sum = p;
#pragma unroll
      for (int o = 32; o; o >>= 1) sum += __shfl_xor(sum, o);
      if (l == 0) red[8 + w] = sum;
      __syncthreads();
      float tot = red[8];
#pragma unroll
      for (int qq = 9; qq < 16; ++qq) tot += red[qq];
      float inv = 1.f / tot;
      if (t < 400) a_out[obase + t] = p * inv;
      __syncthreads();
      float acc2 = 0.f;
#pragma unroll 4
      for (int s = 0; s < 400; ++s)
        acc2 += es[s] * (float)mb[(size_t)s * 512 + t];
      float cval = acc2 * inv;
      unsigned cu = f16bits(cval);
      unsigned other = __shfl_xor(cu, 1);
      if (!(t & 1)) {
        unsigned pack = cu | (other << 16);
        int kg = 512 + t;   // even
        unsigned* dst = (unsigned*)((char*)(HCzT + (size_t)(ts + 1) * 32768)
                                    + (((kg >> 3) * 32 + q) << 4) + ((kg & 7) << 1));
        ASTORE32(dst, pack);
        *(unsigned*)(HC_A + ((size_t)ts * 32 + q) * 1024 + kg) = pack;
      }
    }
    gbar(bar + ts * 32 + 16);
  }
}

// ---------------- coverage ----------------
__global__ void cov_kernel(const float* __restrict__ attn, float* __restrict__ cov){
  int idx = blockIdx.x * 256 + threadIdx.x;
  if (idx >= 12800) return;
  float acc = 0.f;
  for (int t = 0; t < 32; ++t) {
    cov[(size_t)t * 12800 + idx] = acc;
    acc += attn[(size_t)t * 12800 + idx];
  }
}

// ---------------- pointer scatter-max patch ----------------
__global__ __launch_bounds__(512) void pointer_kernel(
    const int* __restrict__ ext, const float* __restrict__ energ, float* __restrict__ logits)
{
  __shared__ int ids[400];
  __shared__ float es[400];
  int tb = blockIdx.x;
  int b = tb & 31;
  int tt = tb >> 5;
  int t = threadIdx.x;
  if (t < 400) {
    ids[t] = ext[b * 400 + t];
    es[t] = energ[(size_t)tt * 12800 + b * 400 + t];
  }
  __syncthreads();
  if (t < 400) {
    int id = ids[t];
    bool first = true;
    for (int s = 0; s < t; ++s) if (ids[s] == id) { first = false; break; }
    if (first) {
      float mx = es[t];
      for (int s = t + 1; s < 400; ++s) if (ids[s] == id) mx = fmaxf(mx, es[s]);
      if (mx != -NEGF) {
        float* p = &logits[(size_t)tb * 45050 + id];
        float base = 0.f;
        if (id < 45000) { float cur = *p; base = (cur == -NEGF) ? 0.f : cur; }
        float nv = base + mx;
        *p = (nv == 0.f) ? -NEGF : nv;
      }
    }
  }
}

// ---------------- host launcher ----------------
extern "C" void kernel_launch(void* const* d_in, const int* in_sizes, int n_in,
                              void* d_out, int out_size, void* d_ws, size_t ws_size,
                              hipStream_t stream) {
  const float* trg   = (const float*)d_in[0];
  const int*   ext   = (const int*)d_in[1];
  const float* inits = (const float*)d_in[2];
  const float* enc   = (const float*)d_in[3];
  const int*   mask  = (const int*)d_in[4];
  const float* W_enc = (const float*)d_in[5];
  const float* b_enc = (const float*)d_in[6];
  const float* W_red = (const float*)d_in[7];
  const float* b_red = (const float*)d_in[8];
  const float* W_ih  = (const float*)d_in[9];
  const float* W_hh  = (const float*)d_in[10];
  const float* b_ih  = (const float*)d_in[11];
  const float* b_hh  = (const float*)d_in[12];
  const float* W_cat = (const float*)d_in[13];
  const float* b_cat = (const float*)d_in[14];
  const float* W_log = (const float*)d_in[15];
  const float* b_log = (const float*)d_in[16];

  float* out = (float*)d_out;
  float* out_logits = out;                       // [1024 x 45050]
  float* out_attn   = out + 46131200;
  float* out_cov    = out_attn + 409600;
  float* out_energy = out_cov + 409600;

  char* ws = (char*)d_ws;
  size_t o = 0;
  auto alloc = [&](size_t bytes) { void* p = ws + o; o += (bytes + 255) & ~(size_t)255; return p; };
  _Float16* mem_h   = (_Float16*)alloc(12800ULL * 512 * 2);
  _Float16* enc_h   = (_Float16*)alloc(12800ULL * 512 * 2);
  _Float16* W_enc_h = (_Float16*)alloc(512ULL * 512 * 2);
  _Float16* emb_h   = (_Float16*)alloc(1024ULL * 320 * 2);
  _Float16* Wr1_h   = (_Float16*)alloc(384ULL * 320 * 2);
  _Float16* X1_h    = (_Float16*)alloc(1024ULL * 320 * 2);
  _Float16* W_ih_h  = (_Float16*)alloc(2048ULL * 320 * 2);
  _Float16* Wr2T_h  = (_Float16*)alloc(512ULL * 320 * 2);
  _Float16* W_cat_h = (_Float16*)alloc(512ULL * 1024 * 2);
  _Float16* W_log_h = (_Float16*)alloc(45056ULL * 512 * 2);
  _Float16* A_log_h = (_Float16*)alloc(1024ULL * 512 * 2);
  _Float16* HCzT    = (_Float16*)alloc(33ULL * 32768 * 2);  // transposed z slabs
  _Float16* HC_A    = (_Float16*)alloc(1024ULL * 1024 * 2); // [ts*32+b][h|ctx] for epilogue
  _Float16* Wz      = (_Float16*)alloc(2048ULL * 1024 * 2); // [Whh | M1]
  float* P        = (float*)alloc(1024ULL * 2048 * 4);
  float* bias_sum = (float*)alloc(2048ULL * 4);
  unsigned* bar   = (unsigned*)alloc(4096);

  auto blocks = [](long total) { return (int)((total + 255) / 256); };

  // init + casts
  init_kernel<<<blocks(327680), 256, 0, stream>>>(inits, b_ih, b_hh, HCzT, bias_sum, X1_h, bar);
  cast_pad_kernel<<<blocks(12800L*512), 256, 0, stream>>>(enc,   enc_h,   12800, 512, 512, 512, 512, 12800L*512);
  cast_pad_kernel<<<blocks(512L*512),   256, 0, stream>>>(W_enc, W_enc_h, 512,   512, 512, 512, 512, 512L*512);
  cast_pad_kernel<<<blocks(384L*320),   256, 0, stream>>>(W_red, Wr1_h,   300,   300, 812, 320, 320, 384L*320);
  cast_pad_kernel<<<blocks(2048L*320),  256, 0, stream>>>(W_ih,  W_ih_h,  2048,  300, 300, 320, 320, 2048L*320);
  cast_pad_kernel<<<blocks(512L*1024),  256, 0, stream>>>(W_cat, W_cat_h, 512,  1024, 1024, 1024, 1024, 512L*1024);
  cast_pad_kernel<<<blocks(45056L*512), 256, 0, stream>>>(W_log, W_log_h, 45000, 512, 512, 512, 512, 45056L*512);
  cast_pad_kernel<<<blocks(2048L*512),  256, 0, stream>>>(W_hh,  Wz,      2048,  512, 512, 512, 1024, 2048L*512);
  cast_emb_kernel<<<blocks(1024L*320), 256, 0, stream>>>(trg, emb_h);
  cast_wr2t_kernel<<<blocks(512L*320), 256, 0, stream>>>(W_red, Wr2T_h);

  // batched pre-GEMMs
  gemm_f16<1><<<400, 256, 0, stream>>>(enc_h, W_enc_h, nullptr, mem_h, b_enc, 512, 512, 512, 100);
  gemm_f16<1><<<24,  256, 0, stream>>>(emb_h, Wr1_h, nullptr, X1_h, b_red, 300, 320, 320, 8);
  gemm_f16<0><<<128, 256, 0, stream>>>(X1_h, W_ih_h, P, nullptr, bias_sum, 2048, 320, 2048, 8);
  gemm_f16<1><<<64,  256, 0, stream>>>(W_ih_h, Wr2T_h, nullptr, Wz + 512, nullptr, 512, 320, 1024, 16);

  // fused persistent recurrence (one launch, fence-free barriers)
  fused_loop<<<32, 512, 0, stream>>>(mem_h, HCzT, HC_A, Wz, P, inits, mask,
                                     out_energy, out_attn, bar);

  // epilogue
  cov_kernel<<<50, 256, 0, stream>>>(out_attn, out_cov);
  gemm_f16<2><<<32, 256, 0, stream>>>(HC_A, W_cat_h, nullptr, A_log_h, b_cat, 512, 1024, 512, 8);
  gemm_f16<3><<<2816, 256, 0, stream>>>(A_log_h, W_log_h, out_logits, nullptr, b_log, 45000, 512, 45050, 8);
  pointer_kernel<<<1024, 512, 0, stream>>>(ext, out_energy, out_logits);
}

// Round 6
// 1368.243 us; speedup vs baseline: 1.9987x; 1.2166x over previous
//
#include <hip/hip_runtime.h>
#include <hip/hip_bf16.h>

typedef _Float16 h2 __attribute__((ext_vector_type(2)));
typedef _Float16 h8 __attribute__((ext_vector_type(8)));
typedef __attribute__((ext_vector_type(4))) float floatx4;

#define NEGF 1.0e12f

#if __has_builtin(__builtin_amdgcn_fdot2)
#define DOT2(a,b,c) __builtin_amdgcn_fdot2((a),(b),(c),false)
#else
static __device__ __forceinline__ float DOT2(h2 a, h2 b, float c){
  return c + (float)a[0]*(float)b[0] + (float)a[1]*(float)b[1];
}
#endif

__device__ __forceinline__ float dot8(h8 a, h8 b, float c){
  h2 a0 = {a[0],a[1]}, a1 = {a[2],a[3]}, a2 = {a[4],a[5]}, a3 = {a[6],a[7]};
  h2 b0 = {b[0],b[1]}, b1 = {b[2],b[3]}, b2 = {b[4],b[5]}, b3 = {b[6],b[7]};
  c = DOT2(a0,b0,c); c = DOT2(a1,b1,c); c = DOT2(a2,b2,c); c = DOT2(a3,b3,c);
  return c;
}

__device__ __forceinline__ unsigned f16bits(float x){
  union { _Float16 h; unsigned short u; } cv; cv.h = (_Float16)x; return (unsigned)cv.u;
}

#define GLD_LDS16(g, l) __builtin_amdgcn_global_load_lds( \
    (const __attribute__((address_space(1))) void*)(g),   \
    (__attribute__((address_space(3))) void*)(l), 16, 0, 0)

#define ALOAD64(p)    __hip_atomic_load((p), __ATOMIC_RELAXED, __HIP_MEMORY_SCOPE_AGENT)
#define ASTORE32(p,v) __hip_atomic_store((p), (v), __ATOMIC_RELAXED, __HIP_MEMORY_SCOPE_AGENT)

// ---------------- generic f16 MFMA GEMM: C[M,N] = A[M,K] @ B[N,K]^T ----------------
// bn = bid % ntn, bm = bid / ntn. For EPI3 (ntn=352, 352%8==0) all bm-tiles of a
// given bn share bid%8 -> same XCD -> B-tile fetched ~once per XCD L2.
template<int EPI>
__global__ __launch_bounds__(256) void gemm_f16(
    const _Float16* __restrict__ A, const _Float16* __restrict__ B,
    float* __restrict__ Cf, _Float16* __restrict__ Ch,
    const float* __restrict__ bias, int N, int K, int ldc, int ntn)
{
  __shared__ char smem[32768];
  _Float16* Al = (_Float16*)smem;
  _Float16* Bl = (_Float16*)(smem + 16384);
  int bid = blockIdx.x;
  int bn = bid % ntn, bm = bid / ntn;
  int t = threadIdx.x;
  int w = t >> 6, l = t & 63;

  floatx4 acc[4][4];
#pragma unroll
  for (int i = 0; i < 4; ++i)
#pragma unroll
    for (int j = 0; j < 4; ++j) acc[i][j] = (floatx4){0.f, 0.f, 0.f, 0.f};

  const char* Ab = (const char*)A + (size_t)bm * 128 * K * 2;
  const char* Bb = (const char*)B + (size_t)bn * 128 * K * 2;
  const int rowb = K * 2;
  const int r0 = t >> 3;
  const int cbyte = ((t & 7) * 16) ^ (((t >> 3) & 7) << 4);
  char* AlB = (char*)Al;
  char* BlB = (char*)Bl;
  const int wm = (w >> 1) * 64, wn = (w & 1) * 64;

  for (int kt = 0; kt < K; kt += 64) {
    __syncthreads();
#pragma unroll
    for (int c = 0; c < 4; ++c) {
      int row = c * 32 + r0;
      GLD_LDS16(Ab + (size_t)row * rowb + kt * 2 + cbyte, AlB + c * 4096 + t * 16);
      GLD_LDS16(Bb + (size_t)row * rowb + kt * 2 + cbyte, BlB + c * 4096 + t * 16);
    }
    __syncthreads();
#pragma unroll
    for (int kk = 0; kk < 64; kk += 32) {
      h8 af[4], bfv[4];
#pragma unroll
      for (int i = 0; i < 4; ++i) {
        int ra = wm + i * 16 + (l & 15);
        int cb = ((kk << 1) + ((l >> 4) << 4)) ^ ((ra & 7) << 4);
        af[i] = *(const h8*)(AlB + ra * 128 + cb);
      }
#pragma unroll
      for (int j = 0; j < 4; ++j) {
        int ra = wn + j * 16 + (l & 15);
        int cb = ((kk << 1) + ((l >> 4) << 4)) ^ ((ra & 7) << 4);
        bfv[j] = *(const h8*)(BlB + ra * 128 + cb);
      }
#pragma unroll
      for (int i = 0; i < 4; ++i)
#pragma unroll
        for (int j = 0; j < 4; ++j)
          acc[i][j] = __builtin_amdgcn_mfma_f32_16x16x32_f16(af[i], bfv[j], acc[i][j], 0, 0, 0);
    }
  }

  if (EPI == 3) {
    float* Cs = (float*)smem;
#pragma unroll
    for (int half = 0; half < 2; ++half) {
      __syncthreads();
      if ((w >> 1) == half) {
        int rbase = ((l >> 4) << 2);
#pragma unroll
        for (int i = 0; i < 4; ++i)
#pragma unroll
          for (int j = 0; j < 4; ++j)
#pragma unroll
            for (int r = 0; r < 4; ++r)
              Cs[(i * 16 + rbase + r) * 128 + wn + j * 16 + (l & 15)] = acc[i][j][r];
      }
      __syncthreads();
#pragma unroll
      for (int rr = 0; rr < 16; ++rr) {
        int row = rr * 4 + w;
        int grow = bm * 128 + half * 64 + row;
        int cc = bn * 128 + 2 * l;
        float2 v = *(float2*)&Cs[row * 128 + 2 * l];
        float vv0, vv1;
        if (cc < N)     { float x0 = v.x + bias[cc];     vv0 = (x0 == 0.f) ? -NEGF : x0; } else vv0 = -NEGF;
        if (cc + 1 < N) { float x1 = v.y + bias[cc + 1]; vv1 = (x1 == 0.f) ? -NEGF : x1; } else vv1 = -NEGF;
        float* orow = Cf + (size_t)grow * ldc;
        if (cc + 1 < ldc) { float2 o; o.x = vv0; o.y = vv1; *(float2*)(orow + cc) = o; }
        else if (cc < ldc) orow[cc] = vv0;
      }
    }
  } else {
    int mbase = bm * 128 + wm + ((l >> 4) << 2);
    int nbase = bn * 128 + wn + (l & 15);
#pragma unroll
    for (int j = 0; j < 4; ++j) {
      int col = nbase + j * 16;
#pragma unroll
      for (int i = 0; i < 4; ++i) {
#pragma unroll
        for (int r = 0; r < 4; ++r) {
          int row = mbase + i * 16 + r;
          float v = acc[i][j][r];
          if (col < N) {
            float bv = bias ? bias[col] : 0.f;
            if (EPI == 0)      Cf[(size_t)row * ldc + col] = v + bv;
            else if (EPI == 1) Ch[(size_t)row * ldc + col] = (_Float16)(v + bv);
            else               Ch[(size_t)row * ldc + col] = (_Float16)tanhf(v + bv);
          }
        }
      }
    }
  }
}

// ---------------- cast / pad kernels ----------------
__global__ void cast_pad_kernel(const float* __restrict__ src, _Float16* __restrict__ dst,
                                int R, int C, int ld_src, int Cpad, int ld_dst, long total){
  long i = (long)blockIdx.x * 256 + threadIdx.x;
  if (i >= total) return;
  int r = (int)(i / Cpad), c = (int)(i % Cpad);
  float v = (r < R && c < C) ? src[(size_t)r * ld_src + c] : 0.f;
  dst[(size_t)r * ld_dst + c] = (_Float16)v;
}

__global__ void cast_emb_kernel(const float* __restrict__ trg, _Float16* __restrict__ dst){
  int i = blockIdx.x * 256 + threadIdx.x;
  if (i >= 1024 * 320) return;
  int m = i / 320, e = i % 320;
  int tt = m >> 5, b = m & 31;
  float v = (e < 300) ? trg[((size_t)b * 32 + tt) * 300 + e] : 0.f;
  dst[i] = (_Float16)v;
}

__global__ void cast_wr2t_kernel(const float* __restrict__ wred, _Float16* __restrict__ dst){
  int i = blockIdx.x * 256 + threadIdx.x;
  if (i >= 512 * 320) return;
  int h = i / 320, e = i % 320;
  float v = (e < 300) ? wred[(size_t)e * 812 + 300 + h] : 0.f;
  dst[i] = (_Float16)v;
}

// HCzT slab: unit u = kc*32 + b (16B each), holds z[b][kc*8 .. kc*8+8]
__global__ void init_kernel(const float* __restrict__ h0, const float* __restrict__ b_ih,
                            const float* __restrict__ b_hh,
                            _Float16* __restrict__ HCzT, float* __restrict__ bias_sum,
                            _Float16* __restrict__ X1h, unsigned* __restrict__ bar){
  int i = blockIdx.x * 256 + threadIdx.x;
  if (i < 32768) {
    int unit = i >> 3, pos = i & 7;
    int kc = unit >> 5, b = unit & 31;
    int k = kc * 8 + pos;
    HCzT[i] = (k < 512) ? (_Float16)h0[b * 512 + k] : (_Float16)0.f;
  }
  if (i < 2048)  bias_sum[i] = b_ih[i] + b_hh[i];
  if (i < 327680) X1h[i] = (_Float16)0.f;
  if (i < 1024) bar[i] = 0u;
}

// ---------------- fence-free flag barrier ----------------
__device__ __forceinline__ void gbar(unsigned* cnt){
  asm volatile("s_waitcnt vmcnt(0)" ::: "memory");
  __syncthreads();
  if (threadIdx.x == 0) {
    __hip_atomic_fetch_add(cnt, 1u, __ATOMIC_RELAXED, __HIP_MEMORY_SCOPE_AGENT);
    while (__hip_atomic_load(cnt, __ATOMIC_RELAXED, __HIP_MEMORY_SCOPE_AGENT) < 32u)
      __builtin_amdgcn_s_sleep(1);
  }
  __syncthreads();
  asm volatile("" ::: "memory");
}

// ---------------- fused persistent recurrence: 32 blocks x 512 threads ----------------
__global__ __launch_bounds__(512, 1) void fused_loop(
    const _Float16* __restrict__ memh, _Float16* __restrict__ HCzT,
    _Float16* __restrict__ HC_A, const _Float16* __restrict__ Wz,
    const float* __restrict__ P, const float* __restrict__ inits,
    const int* __restrict__ mask, float* __restrict__ e_out,
    float* __restrict__ a_out, float* __restrict__ c_out, unsigned* __restrict__ bar)
{
  __shared__ char smem[32768];      // phase A: gl[8192] floats; phase B: 2x16KB stage tiles
  __shared__ float es[400];
  __shared__ float red[16];
  __shared__ float cum[400];
  __shared__ _Float16 hh[512];

  float* gl = (float*)smem;
  const int q = blockIdx.x, t = threadIdx.x;
  const int w = t >> 6, l = t & 63;
  const int mw = w >> 2, nw = w & 3;    // batch-half, k-quarter

  if (t < 400) cum[t] = 0.f;

  float creg = inits[(t >> 4) * 512 + q * 16 + (t & 15)];   // c0 = h0
  const _Float16* mb = memh + (size_t)q * 400 * 512;
  const char* mbB = (const char*)mb;

  // per-gate weight row base (loaded fresh each step; L2-resident)
  const _Float16* wbase[4];
#pragma unroll
  for (int s = 0; s < 4; ++s)
    wbase[s] = Wz + (size_t)(s * 512 + q * 16 + (l & 15)) * 1024 + nw * 256 + ((l >> 4) << 3);

  __syncthreads();

  for (int ts = 0; ts < 32; ++ts) {
    // ======== phase A: gates MFMA ========
    {
      unsigned long long* zsrc = (unsigned long long*)(HCzT + (size_t)ts * 32768);
      floatx4 acc[4];
#pragma unroll
      for (int s = 0; s < 4; ++s) acc[s] = (floatx4){0.f, 0.f, 0.f, 0.f};
#pragma unroll
      for (int kk8 = 0; kk8 < 8; ++kk8) {
        int unit = ((nw * 8 + kk8) * 4 + (l >> 4)) * 32 + mw * 16 + (l & 15);
        union { unsigned long long u[2]; h8 v; } za;
        za.u[0] = ALOAD64(zsrc + (size_t)unit * 2);
        za.u[1] = ALOAD64(zsrc + (size_t)unit * 2 + 1);
#pragma unroll
        for (int s = 0; s < 4; ++s) {
          h8 wv = *(const h8*)(wbase[s] + kk8 * 32);
          acc[s] = __builtin_amdgcn_mfma_f32_16x16x32_f16(za.v, wv, acc[s], 0, 0, 0);
        }
      }
#pragma unroll
      for (int s = 0; s < 4; ++s)
#pragma unroll
        for (int r = 0; r < 4; ++r) {
          int b = mw * 16 + ((l >> 4) << 2) + r;
          gl[(s * 4 + nw) * 512 + b * 16 + (l & 15)] = acc[s][r];
        }
    }
    __syncthreads();
    // ---- LSTM pointwise: thread t -> (b = t>>4, j16 = t&15) ----
    {
      int b = t >> 4, j16 = t & 15;
      const float* Pr = P + ((size_t)ts * 32 + b) * 2048 + q * 16 + j16;
      float g4[4];
#pragma unroll
      for (int s = 0; s < 4; ++s)
        g4[s] = gl[(s * 4 + 0) * 512 + t] + gl[(s * 4 + 1) * 512 + t]
              + gl[(s * 4 + 2) * 512 + t] + gl[(s * 4 + 3) * 512 + t] + Pr[s * 512];
      float ig = 1.f / (1.f + expf(-g4[0]));
      float fg = 1.f / (1.f + expf(-g4[1]));
      float og = 1.f / (1.f + expf(-g4[3]));
      float cn = fg * creg + ig * tanhf(g4[2]);
      float hn = og * tanhf(cn);
      creg = cn;
      unsigned hu = f16bits(hn);
      unsigned other = __shfl_xor(hu, 1);
      if (!(t & 1)) {
        unsigned pack = hu | (other << 16);
        int j = q * 16 + j16;
        unsigned* dst = (unsigned*)((char*)(HCzT + (size_t)(ts + 1) * 32768)
                                    + (((j >> 3) * 32 + b) << 4) + ((j & 7) << 1));
        ASTORE32(dst, pack);
        *(unsigned*)(HC_A + ((size_t)ts * 32 + b) * 1024 + j) = pack;
      }
    }
    gbar(bar + ts * 32);

    // ======== phase B: attention for batch q ========
    size_t obase = (size_t)ts * 12800 + q * 400;
    {
      // h -> LDS
      if (t < 64) {
        unsigned long long* hsrc = (unsigned long long*)(HCzT + (size_t)(ts + 1) * 32768);
        union { unsigned long long u[2]; h8 v; } ha;
        ha.u[0] = ALOAD64(hsrc + ((size_t)t * 32 + q) * 2);
        ha.u[1] = ALOAD64(hsrc + ((size_t)t * 32 + q) * 2 + 1);
        *(h8*)&hh[t * 8] = ha.v;
      }
      __syncthreads();

      // energy: 4 lanes per s-row (d-chunks of 128), 2-level shuffle reduce
      {
        int g = l >> 2, c = l & 3;
#pragma unroll
        for (int r = 0; r < 4; ++r) {
          int sr = r * 16 + g;
          if (sr < 50) {
            int s = w * 50 + sr;
            const _Float16* row = mb + (size_t)s * 512 + c * 128;
            float e = 0.f;
#pragma unroll
            for (int k = 0; k < 16; ++k)
              e = dot8(*(const h8*)(row + k * 8), *(const h8*)&hh[c * 128 + k * 8], e);
            e += __shfl_xor(e, 1);
            e += __shfl_xor(e, 2);
            if (c == 0) {
              if (mask[q * 400 + s] == 0) e = -NEGF;
              es[s] = e;
            }
          }
        }
      }
      __syncthreads();
      if (t < 400) e_out[obase + t] = es[t];

      // softmax over es[400]
      float v = (t < 400) ? es[t] : -3.4e38f;
      float m = v;
#pragma unroll
      for (int o = 32; o; o >>= 1) m = fmaxf(m, __shfl_xor(m, o));
      if (l == 0) red[w] = m;
      __syncthreads();
      m = red[0];
#pragma unroll
      for (int qq = 1; qq < 8; ++qq) m = fmaxf(m, red[qq]);
      float p = (t < 400) ? expf(v - m) : 0.f;
      float sum = p;
#pragma unroll
      for (int o = 32; o; o >>= 1) sum += __shfl_xor(sum, o);
      if (l == 0) red[8 + w] = sum;
      __syncthreads();
      float tot = red[8];
#pragma unroll
      for (int qq = 9; qq < 16; ++qq) tot += red[qq];
      float inv = 1.f / tot;
      float aval = p * inv;
      if (t < 400) {
        es[t] = aval;                       // normalized attn for ctx pass
        a_out[obase + t] = aval;
        c_out[obase + t] = cum[t];          // coverage (pre-update)
        cum[t] += aval;
      }
      __syncthreads();

      // context: LDS-staged 16-row tiles, double-buffered
      _Float16* stg = (_Float16*)smem;      // 2 x 16KB
      {
        // stage tile 0
        GLD_LDS16(mbB + 0 * 8192 + t * 16, smem + 0 * 8192 + t * 16);
        GLD_LDS16(mbB + 1 * 8192 + t * 16, smem + 1 * 8192 + t * 16);
      }
      float acc0 = 0.f, acc1 = 0.f;
      for (int T = 0; T < 25; ++T) {
        __syncthreads();   // stage T complete (vmcnt drained at barrier)
        if (T + 1 < 25) {
          int nb = (T + 1) & 1;
          const char* src = mbB + (size_t)(T + 1) * 16384;
          GLD_LDS16(src + 0 * 8192 + t * 16, smem + nb * 16384 + 0 * 8192 + t * 16);
          GLD_LDS16(src + 1 * 8192 + t * 16, smem + nb * 16384 + 1 * 8192 + t * 16);
        }
        const _Float16* Ls = stg + (size_t)(T & 1) * 8192;
#pragma unroll
        for (int j = 0; j < 16; j += 2) {
          acc0 += es[T * 16 + j]     * (float)Ls[j * 512 + t];
          acc1 += es[T * 16 + j + 1] * (float)Ls[(j + 1) * 512 + t];
        }
      }
      float cval = acc0 + acc1;
      unsigned cu = f16bits(cval);
      unsigned other = __shfl_xor(cu, 1);
      if (!(t & 1)) {
        unsigned pack = cu | (other << 16);
        int kg = 512 + t;
        unsigned* dst = (unsigned*)((char*)(HCzT + (size_t)(ts + 1) * 32768)
                                    + (((kg >> 3) * 32 + q) << 4) + ((kg & 7) << 1));
        ASTORE32(dst, pack);
        *(unsigned*)(HC_A + ((size_t)ts * 32 + q) * 1024 + kg) = pack;
      }
    }
    gbar(bar + ts * 32 + 16);
  }
}

// ---------------- pointer scatter-max patch ----------------
__global__ __launch_bounds__(512) void pointer_kernel(
    const int* __restrict__ ext, const float* __restrict__ energ, float* __restrict__ logits)
{
  __shared__ int ids[400];
  __shared__ float es[400];
  int tb = blockIdx.x;
  int b = tb & 31;
  int tt = tb >> 5;
  int t = threadIdx.x;
  if (t < 400) {
    ids[t] = ext[b * 400 + t];
    es[t] = energ[(size_t)tt * 12800 + b * 400 + t];
  }
  __syncthreads();
  if (t < 400) {
    int id = ids[t];
    bool first = true;
    for (int s = 0; s < t; ++s) if (ids[s] == id) { first = false; break; }
    if (first) {
      float mx = es[t];
      for (int s = t + 1; s < 400; ++s) if (ids[s] == id) mx = fmaxf(mx, es[s]);
      if (mx != -NEGF) {
        float* p = &logits[(size_t)tb * 45050 + id];
        float base = 0.f;
        if (id < 45000) { float cur = *p; base = (cur == -NEGF) ? 0.f : cur; }
        float nv = base + mx;
        *p = (nv == 0.f) ? -NEGF : nv;
      }
    }
  }
}

// ---------------- host launcher ----------------
extern "C" void kernel_launch(void* const* d_in, const int* in_sizes, int n_in,
                              void* d_out, int out_size, void* d_ws, size_t ws_size,
                              hipStream_t stream) {
  const float* trg   = (const float*)d_in[0];
  const int*   ext   = (const int*)d_in[1];
  const float* inits = (const float*)d_in[2];
  const float* enc   = (const float*)d_in[3];
  const int*   mask  = (const int*)d_in[4];
  const float* W_enc = (const float*)d_in[5];
  const float* b_enc = (const float*)d_in[6];
  const float* W_red = (const float*)d_in[7];
  const float* b_red = (const float*)d_in[8];
  const float* W_ih  = (const float*)d_in[9];
  const float* W_hh  = (const float*)d_in[10];
  const float* b_ih  = (const float*)d_in[11];
  const float* b_hh  = (const float*)d_in[12];
  const float* W_cat = (const float*)d_in[13];
  const float* b_cat = (const float*)d_in[14];
  const float* W_log = (const float*)d_in[15];
  const float* b_log = (const float*)d_in[16];

  float* out = (float*)d_out;
  float* out_logits = out;                       // [1024 x 45050]
  float* out_attn   = out + 46131200;
  float* out_cov    = out_attn + 409600;
  float* out_energy = out_cov + 409600;

  char* ws = (char*)d_ws;
  size_t o = 0;
  auto alloc = [&](size_t bytes) { void* p = ws + o; o += (bytes + 255) & ~(size_t)255; return p; };
  _Float16* mem_h   = (_Float16*)alloc(12800ULL * 512 * 2);
  _Float16* enc_h   = (_Float16*)alloc(12800ULL * 512 * 2);
  _Float16* W_enc_h = (_Float16*)alloc(512ULL * 512 * 2);
  _Float16* emb_h   = (_Float16*)alloc(1024ULL * 320 * 2);
  _Float16* Wr1_h   = (_Float16*)alloc(384ULL * 320 * 2);
  _Float16* X1_h    = (_Float16*)alloc(1024ULL * 320 * 2);
  _Float16* W_ih_h  = (_Float16*)alloc(2048ULL * 320 * 2);
  _Float16* Wr2T_h  = (_Float16*)alloc(512ULL * 320 * 2);
  _Float16* W_cat_h = (_Float16*)alloc(512ULL * 1024 * 2);
  _Float16* W_log_h = (_Float16*)alloc(45056ULL * 512 * 2);
  _Float16* A_log_h = (_Float16*)alloc(1024ULL * 512 * 2);
  _Float16* HCzT    = (_Float16*)alloc(33ULL * 32768 * 2);
  _Float16* HC_A    = (_Float16*)alloc(1024ULL * 1024 * 2);
  _Float16* Wz      = (_Float16*)alloc(2048ULL * 1024 * 2); // [Whh | M1]
  float* P        = (float*)alloc(1024ULL * 2048 * 4);
  float* bias_sum = (float*)alloc(2048ULL * 4);
  unsigned* bar   = (unsigned*)alloc(4096);

  auto blocks = [](long total) { return (int)((total + 255) / 256); };

  // init + casts
  init_kernel<<<blocks(327680), 256, 0, stream>>>(inits, b_ih, b_hh, HCzT, bias_sum, X1_h, bar);
  cast_pad_kernel<<<blocks(12800L*512), 256, 0, stream>>>(enc,   enc_h,   12800, 512, 512, 512, 512, 12800L*512);
  cast_pad_kernel<<<blocks(512L*512),   256, 0, stream>>>(W_enc, W_enc_h, 512,   512, 512, 512, 512, 512L*512);
  cast_pad_kernel<<<blocks(384L*320),   256, 0, stream>>>(W_red, Wr1_h,   300,   300, 812, 320, 320, 384L*320);
  cast_pad_kernel<<<blocks(2048L*320),  256, 0, stream>>>(W_ih,  W_ih_h,  2048,  300, 300, 320, 320, 2048L*320);
  cast_pad_kernel<<<blocks(512L*1024),  256, 0, stream>>>(W_cat, W_cat_h, 512,  1024, 1024, 1024, 1024, 512L*1024);
  cast_pad_kernel<<<blocks(45056L*512), 256, 0, stream>>>(W_log, W_log_h, 45000, 512, 512, 512, 512, 45056L*512);
  cast_pad_kernel<<<blocks(2048L*512),  256, 0, stream>>>(W_hh,  Wz,      2048,  512, 512, 512, 1024, 2048L*512);
  cast_emb_kernel<<<blocks(1024L*320), 256, 0, stream>>>(trg, emb_h);
  cast_wr2t_kernel<<<blocks(512L*320), 256, 0, stream>>>(W_red, Wr2T_h);

  // batched pre-GEMMs (grid = ntm*ntn, last arg = ntn)
  gemm_f16<1><<<400, 256, 0, stream>>>(enc_h, W_enc_h, nullptr, mem_h, b_enc, 512, 512, 512, 4);
  gemm_f16<1><<<24,  256, 0, stream>>>(emb_h, Wr1_h, nullptr, X1_h, b_red, 300, 320, 320, 3);
  gemm_f16<0><<<128, 256, 0, stream>>>(X1_h, W_ih_h, P, nullptr, bias_sum, 2048, 320, 2048, 16);
  gemm_f16<1><<<64,  256, 0, stream>>>(W_ih_h, Wr2T_h, nullptr, Wz + 512, nullptr, 512, 320, 1024, 4);

  // fused persistent recurrence (coverage fused in)
  fused_loop<<<32, 512, 0, stream>>>(mem_h, HCzT, HC_A, Wz, P, inits, mask,
                                     out_energy, out_attn, out_cov, bar);

  // epilogue
  gemm_f16<2><<<32, 256, 0, stream>>>(HC_A, W_cat_h, nullptr, A_log_h, b_cat, 512, 1024, 512, 4);
  gemm_f16<3><<<2816, 256, 0, stream>>>(A_log_h, W_log_h, out_logits, nullptr, b_log, 45000, 512, 45050, 352);
  pointer_kernel<<<1024, 512, 0, stream>>>(ext, out_energy, out_logits);
}